// Round 1
// baseline (11755.698 us; speedup 1.0000x reference)
//
#include <hip/hip_runtime.h>

#define NN 100000
#define NE 1600000
#define NB 500

// ---------------- degree / dinv / counts ----------------

__global__ void deg_count_k(const int* __restrict__ ei,
                            int* __restrict__ deg_td, int* __restrict__ deg_bu) {
    int e = blockIdx.x * 256 + threadIdx.x;
    if (e >= NE) return;
    atomicAdd(&deg_td[ei[NE + e]], 1);   // td: deg on dst = edge_index[1]
    atomicAdd(&deg_bu[ei[e]], 1);        // bu: deg on dst_param = edge_index[0]
}

__global__ void make_dinv_k(const int* __restrict__ deg_td, const int* __restrict__ deg_bu,
                            float* __restrict__ dinv_td, float* __restrict__ dinv_bu) {
    int v = blockIdx.x * 256 + threadIdx.x;
    if (v >= NN) return;
    dinv_td[v] = 1.0f / sqrtf((float)(deg_td[v] + 1));
    dinv_bu[v] = 1.0f / sqrtf((float)(deg_bu[v] + 1));
}

__global__ void count_nodes_k(const int* __restrict__ batch, int* __restrict__ cnt) {
    int v = blockIdx.x * 256 + threadIdx.x;
    if (v >= NN) return;
    atomicAdd(&cnt[batch[v]], 1);
}

// ---------------- GEMM: [N,128] @ [128,128] ----------------
// MODE 0: A = concat(x[v], x_da[v])            (conv1 input)
// MODE 1: A = relu(inA[v]), epilogue += rootmix[batch[v]]   (conv2, W = first 128 rows of w2)
template <int MODE>
__global__ __launch_bounds__(256) void gemm128_k(
    const float* __restrict__ x, const float* __restrict__ xda,
    const float* __restrict__ inA,
    const float* __restrict__ W,
    const float* __restrict__ rootmix, const int* __restrict__ batch,
    float* __restrict__ out) {
    __shared__ float As[32][128];   // 16 KB
    __shared__ float Ws[64][128];   // 32 KB  (K staged in 2 halves) -> 48KB, 3 blocks/CU
    const int t = threadIdx.x;
    const int row0 = blockIdx.x * 32;

    // load A tile (32 rows x 128)
#pragma unroll
    for (int i = 0; i < 4; i++) {
        int idx = t + i * 256;           // 0..1023 float4
        int r = idx >> 5, c4 = idx & 31;
        int v = row0 + r;
        float4 a;
        if (MODE == 0) {
            a = (c4 < 24) ? ((const float4*)(x + (size_t)v * 96))[c4]
                          : ((const float4*)(xda + (size_t)v * 32))[c4 - 24];
        } else {
            a = ((const float4*)(inA + (size_t)v * 128))[c4];
            a.x = fmaxf(a.x, 0.f); a.y = fmaxf(a.y, 0.f);
            a.z = fmaxf(a.z, 0.f); a.w = fmaxf(a.w, 0.f);
        }
        *((float4*)&As[r][c4 * 4]) = a;
    }

    const int cg = (t & 31) * 4;   // 4 cols, lane-contiguous -> coalesced stores
    const int rg = (t >> 5) * 4;   // 4 rows
    float acc[4][4] = {};
    const float4* W4 = (const float4*)W;

    for (int kb = 0; kb < 2; kb++) {
        __syncthreads();   // A visible (kb=0) / prev readers done (kb=1)
#pragma unroll
        for (int i = 0; i < 8; i++) {
            int idx = t + i * 256;       // 0..2047 float4
            ((float4*)Ws)[idx] = W4[kb * 2048 + idx];
        }
        __syncthreads();
#pragma unroll 4
        for (int k = 0; k < 64; k += 4) {
            const int kg = kb * 64 + k;
            float4 a0 = *(const float4*)&As[rg + 0][kg];
            float4 a1 = *(const float4*)&As[rg + 1][kg];
            float4 a2 = *(const float4*)&As[rg + 2][kg];
            float4 a3 = *(const float4*)&As[rg + 3][kg];
            float4 w0 = *(const float4*)&Ws[k + 0][cg];
            float4 w1 = *(const float4*)&Ws[k + 1][cg];
            float4 w2 = *(const float4*)&Ws[k + 2][cg];
            float4 w3 = *(const float4*)&Ws[k + 3][cg];
            float aa[4][4] = {{a0.x,a0.y,a0.z,a0.w},{a1.x,a1.y,a1.z,a1.w},
                              {a2.x,a2.y,a2.z,a2.w},{a3.x,a3.y,a3.z,a3.w}};
            float ww[4][4] = {{w0.x,w0.y,w0.z,w0.w},{w1.x,w1.y,w1.z,w1.w},
                              {w2.x,w2.y,w2.z,w2.w},{w3.x,w3.y,w3.z,w3.w}};
#pragma unroll
            for (int kk = 0; kk < 4; kk++)
#pragma unroll
                for (int i = 0; i < 4; i++)
#pragma unroll
                    for (int j = 0; j < 4; j++)
                        acc[i][j] = fmaf(aa[i][kk], ww[kk][j], acc[i][j]);
        }
    }

#pragma unroll
    for (int i = 0; i < 4; i++) {
        int v = row0 + rg + i;
        float4 o = make_float4(acc[i][0], acc[i][1], acc[i][2], acc[i][3]);
        if (MODE == 1) {
            float4 rm = ((const float4*)(rootmix + (size_t)batch[v] * 128))[cg >> 2];
            o.x += rm.x; o.y += rm.y; o.z += rm.z; o.w += rm.w;
        }
        ((float4*)(out + (size_t)v * 128))[cg >> 2] = o;
    }
}

// ---------------- agg buffer init: agg[v] = h[v]*dinv[v]^2 + bias ----------------
__global__ void agg_init_k(const float* __restrict__ h, const float* __restrict__ dinv,
                           const float* __restrict__ bias, float* __restrict__ agg) {
    size_t i = (size_t)blockIdx.x * 256 + threadIdx.x;   // over N*32 float4
    int v = (int)(i >> 5), c4 = (int)(i & 31);
    float di = dinv[v];
    float sl = di * di;
    float4 hv = ((const float4*)h)[i];
    float4 b = ((const float4*)bias)[c4];
    float4 o;
    o.x = fmaf(hv.x, sl, b.x); o.y = fmaf(hv.y, sl, b.y);
    o.z = fmaf(hv.z, sl, b.z); o.w = fmaf(hv.w, sl, b.w);
    ((float4*)agg)[i] = o;
}

// ---------------- edge aggregation: agg[d] += h[s] * dinv[s]*dinv[d] ----------------
__global__ __launch_bounds__(256) void edge_agg_k(
    const int* __restrict__ sp, const int* __restrict__ dp,
    const float* __restrict__ dinv, const float* __restrict__ h,
    float* __restrict__ agg) {
    long long gid = (long long)blockIdx.x * 256 + threadIdx.x;
    int e = (int)(gid >> 5);
    if (e >= NE) return;
    int lane = (int)(gid & 31);
    int s = sp[e], d = dp[e];
    float norm = dinv[s] * dinv[d];
    float4 hv = ((const float4*)(h + (size_t)s * 128))[lane];
    float* dst = agg + (size_t)d * 128 + lane * 4;
    unsafeAtomicAdd(dst + 0, hv.x * norm);
    unsafeAtomicAdd(dst + 1, hv.y * norm);
    unsafeAtomicAdd(dst + 2, hv.z * norm);
    unsafeAtomicAdd(dst + 3, hv.w * norm);
}

// ---------------- root helpers ----------------
__global__ void extract_root_k(const float* __restrict__ agg, const int* __restrict__ root,
                               float* __restrict__ x2root) {
    int b = blockIdx.x, t = threadIdx.x;
    x2root[(size_t)b * 128 + t] = agg[(size_t)root[b] * 128 + t];
}

// rootmix[b] = relu(x0[root[b]]) @ W2[128:256]
__global__ void rootmix_k(const float* __restrict__ x, const float* __restrict__ xda,
                          const int* __restrict__ root, const float* __restrict__ W2,
                          float* __restrict__ rootmix) {
    __shared__ float xr[128];
    int b = blockIdx.x, t = threadIdx.x;
    int r = root[b];
    float val = (t < 96) ? x[(size_t)r * 96 + t] : xda[(size_t)r * 32 + (t - 96)];
    xr[t] = fmaxf(val, 0.f);
    __syncthreads();
    float acc = 0.f;
#pragma unroll 8
    for (int k = 0; k < 128; k++)
        acc = fmaf(xr[k], W2[(size_t)(128 + k) * 128 + t], acc);
    rootmix[(size_t)b * 128 + t] = acc;
}

// ---------------- graph mean: gbuf[b][boff + c] += relu(agg[v][c]) ----------------
__global__ void gscatter_k(const float* __restrict__ agg, const int* __restrict__ batch,
                           float* __restrict__ gbuf, int boff) {
    size_t i = (size_t)blockIdx.x * 256 + threadIdx.x;   // over N*32 float4
    int v = (int)(i >> 5), c4 = (int)(i & 31);
    int b = batch[v];
    float4 val = ((const float4*)agg)[i];
    float* dst = gbuf + (size_t)b * 512 + boff + c4 * 4;
    unsafeAtomicAdd(dst + 0, fmaxf(val.x, 0.f));
    unsafeAtomicAdd(dst + 1, fmaxf(val.y, 0.f));
    unsafeAtomicAdd(dst + 2, fmaxf(val.z, 0.f));
    unsafeAtomicAdd(dst + 3, fmaxf(val.w, 0.f));
}

__global__ void gfinalize_k(float* __restrict__ gbuf, const int* __restrict__ cnt,
                            const float* __restrict__ x2root, int boff) {
    int b = blockIdx.x, t = threadIdx.x;
    float c = (float)cnt[b];
    gbuf[(size_t)b * 512 + boff + t] /= c;
    gbuf[(size_t)b * 512 + boff + 128 + t] = x2root[(size_t)b * 128 + t];
}

// ---------------- final MLP: [B,512] -> relu(512x256) -> 256x2 ----------------
__global__ void mlp_k(const float* __restrict__ g, const float* __restrict__ w1,
                      const float* __restrict__ b1, const float* __restrict__ w2,
                      const float* __restrict__ b2, float* __restrict__ out) {
    __shared__ float gs[512];
    __shared__ float parts[4][2];
    int b = blockIdx.x, t = threadIdx.x;
    gs[t] = g[(size_t)b * 512 + t];
    gs[t + 256] = g[(size_t)b * 512 + 256 + t];
    __syncthreads();
    float acc = b1[t];
#pragma unroll 8
    for (int k = 0; k < 512; k++)
        acc = fmaf(gs[k], w1[(size_t)k * 256 + t], acc);
    float hv = fmaxf(acc, 0.f);
    float p0 = hv * w2[t * 2 + 0];
    float p1 = hv * w2[t * 2 + 1];
#pragma unroll
    for (int off = 32; off; off >>= 1) {
        p0 += __shfl_down(p0, off);
        p1 += __shfl_down(p1, off);
    }
    int w = t >> 6;
    if ((t & 63) == 0) { parts[w][0] = p0; parts[w][1] = p1; }
    __syncthreads();
    if (t == 0) {
        out[b * 2 + 0] = parts[0][0] + parts[1][0] + parts[2][0] + parts[3][0] + b2[0];
        out[b * 2 + 1] = parts[0][1] + parts[1][1] + parts[2][1] + parts[3][1] + b2[1];
    }
}

// ---------------- launch ----------------
extern "C" void kernel_launch(void* const* d_in, const int* in_sizes, int n_in,
                              void* d_out, int out_size, void* d_ws, size_t ws_size,
                              hipStream_t stream) {
    const float* x     = (const float*)d_in[0];
    const float* xda   = (const float*)d_in[1];
    const int*   ei    = (const int*)d_in[2];
    const int*   batch = (const int*)d_in[3];
    const int*   root  = (const int*)d_in[4];
    const float* td_w1 = (const float*)d_in[5];
    const float* td_b1 = (const float*)d_in[6];
    const float* td_w2 = (const float*)d_in[7];
    const float* td_b2 = (const float*)d_in[8];
    const float* bu_w1 = (const float*)d_in[9];
    const float* bu_b1 = (const float*)d_in[10];
    const float* bu_w2 = (const float*)d_in[11];
    const float* bu_b2 = (const float*)d_in[12];
    const float* mw1   = (const float*)d_in[13];
    const float* mb1   = (const float*)d_in[14];
    const float* mw2   = (const float*)d_in[15];
    const float* mb2   = (const float*)d_in[16];
    float* out = (float*)d_out;

    float* h       = (float*)d_ws;
    float* agg     = h + (size_t)NN * 128;
    float* dinv_td = agg + (size_t)NN * 128;
    float* dinv_bu = dinv_td + NN;
    float* x2root  = dinv_bu + NN;
    float* rootmix = x2root + (size_t)NB * 128;
    float* gbuf    = rootmix + (size_t)NB * 128;
    int*   deg_td  = (int*)(gbuf + (size_t)NB * 512);
    int*   deg_bu  = deg_td + NN;
    int*   cnt     = deg_bu + NN;

    // zero: deg_td, deg_bu, cnt (contiguous) and gbuf
    hipMemsetAsync(deg_td, 0, (size_t)(2 * NN + NB) * sizeof(int), stream);
    hipMemsetAsync(gbuf, 0, (size_t)NB * 512 * sizeof(float), stream);

    deg_count_k<<<(NE + 255) / 256, 256, 0, stream>>>(ei, deg_td, deg_bu);
    make_dinv_k<<<(NN + 255) / 256, 256, 0, stream>>>(deg_td, deg_bu, dinv_td, dinv_bu);
    count_nodes_k<<<(NN + 255) / 256, 256, 0, stream>>>(batch, cnt);

    auto run_branch = [&](const int* sp, const int* dp, const float* dinv,
                          const float* w1, const float* b1,
                          const float* w2, const float* b2, int boff) {
        gemm128_k<0><<<NN / 32, 256, 0, stream>>>(x, xda, nullptr, w1, nullptr, nullptr, h);
        agg_init_k<<<NN / 8, 256, 0, stream>>>(h, dinv, b1, agg);
        edge_agg_k<<<NE / 8, 256, 0, stream>>>(sp, dp, dinv, h, agg);
        extract_root_k<<<NB, 128, 0, stream>>>(agg, root, x2root);
        rootmix_k<<<NB, 128, 0, stream>>>(x, xda, root, w2, rootmix);
        gemm128_k<1><<<NN / 32, 256, 0, stream>>>(nullptr, nullptr, agg, w2, rootmix, batch, h);
        agg_init_k<<<NN / 8, 256, 0, stream>>>(h, dinv, b2, agg);
        edge_agg_k<<<NE / 8, 256, 0, stream>>>(sp, dp, dinv, h, agg);
        gscatter_k<<<NN / 8, 256, 0, stream>>>(agg, batch, gbuf, boff);
        gfinalize_k<<<NB, 128, 0, stream>>>(gbuf, cnt, x2root, boff);
    };

    // g = concat([bu, td]): bu at offset 0, td at offset 256
    run_branch(ei + NE, ei, dinv_bu, bu_w1, bu_b1, bu_w2, bu_b2, 0);
    run_branch(ei, ei + NE, dinv_td, td_w1, td_b1, td_w2, td_b2, 256);

    mlp_k<<<NB, 256, 0, stream>>>(gbuf, mw1, mb1, mw2, mb2, out);
}

// Round 2
// 1814.693 us; speedup vs baseline: 6.4781x; 6.4781x over previous
//
#include <hip/hip_runtime.h>

#define NN 100000
#define NE 1600000
#define NB 500

// ---------------- degree / dinv / counts ----------------

__global__ void deg_count_k(const int* __restrict__ ei,
                            int* __restrict__ deg_td, int* __restrict__ deg_bu) {
    int e = blockIdx.x * 256 + threadIdx.x;
    if (e >= NE) return;
    atomicAdd(&deg_td[ei[NE + e]], 1);   // td: deg on dst = edge_index[1]
    atomicAdd(&deg_bu[ei[e]], 1);        // bu: deg on dst_param = edge_index[0]
}

__global__ void make_dinv_k(const int* __restrict__ deg_td, const int* __restrict__ deg_bu,
                            float* __restrict__ dinv_td, float* __restrict__ dinv_bu) {
    int v = blockIdx.x * 256 + threadIdx.x;
    if (v >= NN) return;
    dinv_td[v] = 1.0f / sqrtf((float)(deg_td[v] + 1));
    dinv_bu[v] = 1.0f / sqrtf((float)(deg_bu[v] + 1));
}

__global__ void count_nodes_k(const int* __restrict__ batch, int* __restrict__ cnt) {
    int v = blockIdx.x * 256 + threadIdx.x;
    if (v >= NN) return;
    atomicAdd(&cnt[batch[v]], 1);
}

// ---------------- exclusive scan of deg -> rowptr (+ cursor copy) ----------------
// One block per array (blockIdx 0: td, 1: bu). 1024 threads, serial chunks.
__global__ __launch_bounds__(1024) void scan_k(
    const int* __restrict__ d0, const int* __restrict__ d1,
    int* __restrict__ r0, int* __restrict__ r1,
    int* __restrict__ c0, int* __restrict__ c1) {
    const int* deg = blockIdx.x ? d1 : d0;
    int* rp  = blockIdx.x ? r1 : r0;
    int* cur = blockIdx.x ? c1 : c0;
    __shared__ int sh[1024];
    __shared__ int carry;
    const int t = threadIdx.x;
    if (t == 0) carry = 0;
    __syncthreads();
    for (int base = 0; base < NN; base += 1024) {
        int i = base + t;
        int v = (i < NN) ? deg[i] : 0;
        sh[t] = v;
        __syncthreads();
#pragma unroll
        for (int off = 1; off < 1024; off <<= 1) {
            int add = (t >= off) ? sh[t - off] : 0;
            __syncthreads();
            sh[t] += add;
            __syncthreads();
        }
        int excl = sh[t] - v;
        int tot = sh[1023];
        if (i < NN) { int val = carry + excl; rp[i] = val; cur[i] = val; }
        __syncthreads();                 // everyone done reading carry
        if (t == 0) carry += tot;
        __syncthreads();
    }
    if (t == 0) rp[NN] = carry;
}

__global__ void csr_fill_k(const int* __restrict__ ei,
                           int* __restrict__ cur_td, int* __restrict__ cur_bu,
                           int* __restrict__ csr_td, int* __restrict__ csr_bu) {
    int e = blockIdx.x * 256 + threadIdx.x;
    if (e >= NE) return;
    int a = ei[e], b = ei[NE + e];       // td: a -> b ; bu: b -> a
    int p = atomicAdd(&cur_td[b], 1); csr_td[p] = a;
    int q = atomicAdd(&cur_bu[a], 1); csr_bu[q] = b;
}

// ---------------- GEMM: [N,128] @ [128,128], output pre-scaled by dinv ----------------
// MODE 0: A = concat(x[v], x_da[v]);            out = (A@W) * dinv[v]
// MODE 1: A = relu(inA[v]);                     out = (A@W + rootmix[batch[v]]) * dinv[v]
template <int MODE>
__global__ __launch_bounds__(256) void gemm128_k(
    const float* __restrict__ x, const float* __restrict__ xda,
    const float* __restrict__ inA,
    const float* __restrict__ W,
    const float* __restrict__ rootmix, const int* __restrict__ batch,
    const float* __restrict__ dinv,
    float* __restrict__ out) {
    __shared__ float As[32][128];   // 16 KB
    __shared__ float Ws[64][128];   // 32 KB
    const int t = threadIdx.x;
    const int row0 = blockIdx.x * 32;

#pragma unroll
    for (int i = 0; i < 4; i++) {
        int idx = t + i * 256;
        int r = idx >> 5, c4 = idx & 31;
        int v = row0 + r;
        float4 a;
        if (MODE == 0) {
            a = (c4 < 24) ? ((const float4*)(x + (size_t)v * 96))[c4]
                          : ((const float4*)(xda + (size_t)v * 32))[c4 - 24];
        } else {
            a = ((const float4*)(inA + (size_t)v * 128))[c4];
            a.x = fmaxf(a.x, 0.f); a.y = fmaxf(a.y, 0.f);
            a.z = fmaxf(a.z, 0.f); a.w = fmaxf(a.w, 0.f);
        }
        *((float4*)&As[r][c4 * 4]) = a;
    }

    const int cg = (t & 31) * 4;
    const int rg = (t >> 5) * 4;
    float acc[4][4] = {};
    const float4* W4 = (const float4*)W;

    for (int kb = 0; kb < 2; kb++) {
        __syncthreads();
#pragma unroll
        for (int i = 0; i < 8; i++) {
            int idx = t + i * 256;
            ((float4*)Ws)[idx] = W4[kb * 2048 + idx];
        }
        __syncthreads();
#pragma unroll 4
        for (int k = 0; k < 64; k += 4) {
            const int kg = kb * 64 + k;
            float4 a0 = *(const float4*)&As[rg + 0][kg];
            float4 a1 = *(const float4*)&As[rg + 1][kg];
            float4 a2 = *(const float4*)&As[rg + 2][kg];
            float4 a3 = *(const float4*)&As[rg + 3][kg];
            float4 w0 = *(const float4*)&Ws[k + 0][cg];
            float4 w1 = *(const float4*)&Ws[k + 1][cg];
            float4 w2 = *(const float4*)&Ws[k + 2][cg];
            float4 w3 = *(const float4*)&Ws[k + 3][cg];
            float aa[4][4] = {{a0.x,a0.y,a0.z,a0.w},{a1.x,a1.y,a1.z,a1.w},
                              {a2.x,a2.y,a2.z,a2.w},{a3.x,a3.y,a3.z,a3.w}};
            float ww[4][4] = {{w0.x,w0.y,w0.z,w0.w},{w1.x,w1.y,w1.z,w1.w},
                              {w2.x,w2.y,w2.z,w2.w},{w3.x,w3.y,w3.z,w3.w}};
#pragma unroll
            for (int kk = 0; kk < 4; kk++)
#pragma unroll
                for (int i = 0; i < 4; i++)
#pragma unroll
                    for (int j = 0; j < 4; j++)
                        acc[i][j] = fmaf(aa[i][kk], ww[kk][j], acc[i][j]);
        }
    }

#pragma unroll
    for (int i = 0; i < 4; i++) {
        int v = row0 + rg + i;
        float dd = dinv[v];
        float4 o = make_float4(acc[i][0], acc[i][1], acc[i][2], acc[i][3]);
        if (MODE == 1) {
            float4 rm = ((const float4*)(rootmix + (size_t)batch[v] * 128))[cg >> 2];
            o.x += rm.x; o.y += rm.y; o.z += rm.z; o.w += rm.w;
        }
        o.x *= dd; o.y *= dd; o.z *= dd; o.w *= dd;
        ((float4*)(out + (size_t)v * 128))[cg >> 2] = o;
    }
}

// ---------------- CSR gather: agg[v] = dinv[v]*(sum_{s in N(v)} hs[s] + hs[v]) + bias ----
// hs = (pre-aggregation features) * dinv, produced by gemm epilogue.
// MODE 0: store row to agg.    MODE 1: relu row, atomicAdd into gbuf[batch[v]].
template <int MODE>
__global__ __launch_bounds__(256) void gather_k(
    const int* __restrict__ rowptr, const int* __restrict__ csr,
    const float* __restrict__ dinv, const float* __restrict__ hs,
    const float* __restrict__ bias,
    float* __restrict__ agg,
    const int* __restrict__ batch, float* __restrict__ gbuf, int boff) {
    int v = blockIdx.x * 8 + (threadIdx.x >> 5);
    if (v >= NN) return;
    const int lane = threadIdx.x & 31;
    int beg = rowptr[v], end = rowptr[v + 1];
    float4 acc = ((const float4*)(hs + (size_t)v * 128))[lane];   // self-loop term
    for (int base = beg; base < end; base += 32) {
        int n = end - base; if (n > 32) n = 32;
        int idx = (lane < n) ? csr[base + lane] : 0;
        for (int i = 0; i < n; i++) {
            int s = __shfl(idx, i, 32);
            float4 hv = ((const float4*)(hs + (size_t)s * 128))[lane];
            acc.x += hv.x; acc.y += hv.y; acc.z += hv.z; acc.w += hv.w;
        }
    }
    float dd = dinv[v];
    float4 b4 = ((const float4*)bias)[lane];
    float4 o;
    o.x = fmaf(acc.x, dd, b4.x); o.y = fmaf(acc.y, dd, b4.y);
    o.z = fmaf(acc.z, dd, b4.z); o.w = fmaf(acc.w, dd, b4.w);
    if (MODE == 0) {
        ((float4*)(agg + (size_t)v * 128))[lane] = o;
    } else {
        float* dst = gbuf + (size_t)batch[v] * 512 + boff + lane * 4;
        unsafeAtomicAdd(dst + 0, fmaxf(o.x, 0.f));
        unsafeAtomicAdd(dst + 1, fmaxf(o.y, 0.f));
        unsafeAtomicAdd(dst + 2, fmaxf(o.z, 0.f));
        unsafeAtomicAdd(dst + 3, fmaxf(o.w, 0.f));
    }
}

// ---------------- root helpers ----------------
__global__ void extract_root_k(const float* __restrict__ agg, const int* __restrict__ root,
                               float* __restrict__ x2root) {
    int b = blockIdx.x, t = threadIdx.x;
    x2root[(size_t)b * 128 + t] = agg[(size_t)root[b] * 128 + t];
}

// rootmix[b] = relu(x0[root[b]]) @ W2[128:256]
__global__ void rootmix_k(const float* __restrict__ x, const float* __restrict__ xda,
                          const int* __restrict__ root, const float* __restrict__ W2,
                          float* __restrict__ rootmix) {
    __shared__ float xr[128];
    int b = blockIdx.x, t = threadIdx.x;
    int r = root[b];
    float val = (t < 96) ? x[(size_t)r * 96 + t] : xda[(size_t)r * 32 + (t - 96)];
    xr[t] = fmaxf(val, 0.f);
    __syncthreads();
    float acc = 0.f;
#pragma unroll 8
    for (int k = 0; k < 128; k++)
        acc = fmaf(xr[k], W2[(size_t)(128 + k) * 128 + t], acc);
    rootmix[(size_t)b * 128 + t] = acc;
}

__global__ void gfinalize_k(float* __restrict__ gbuf, const int* __restrict__ cnt,
                            const float* __restrict__ x2root, int boff) {
    int b = blockIdx.x, t = threadIdx.x;
    float c = (float)cnt[b];
    gbuf[(size_t)b * 512 + boff + t] /= c;
    gbuf[(size_t)b * 512 + boff + 128 + t] = x2root[(size_t)b * 128 + t];
}

// ---------------- final MLP: [B,512] -> relu(512x256) -> 256x2 ----------------
__global__ void mlp_k(const float* __restrict__ g, const float* __restrict__ w1,
                      const float* __restrict__ b1, const float* __restrict__ w2,
                      const float* __restrict__ b2, float* __restrict__ out) {
    __shared__ float gs[512];
    __shared__ float parts[4][2];
    int b = blockIdx.x, t = threadIdx.x;
    gs[t] = g[(size_t)b * 512 + t];
    gs[t + 256] = g[(size_t)b * 512 + 256 + t];
    __syncthreads();
    float acc = b1[t];
#pragma unroll 8
    for (int k = 0; k < 512; k++)
        acc = fmaf(gs[k], w1[(size_t)k * 256 + t], acc);
    float hv = fmaxf(acc, 0.f);
    float p0 = hv * w2[t * 2 + 0];
    float p1 = hv * w2[t * 2 + 1];
#pragma unroll
    for (int off = 32; off; off >>= 1) {
        p0 += __shfl_down(p0, off);
        p1 += __shfl_down(p1, off);
    }
    int w = t >> 6;
    if ((t & 63) == 0) { parts[w][0] = p0; parts[w][1] = p1; }
    __syncthreads();
    if (t == 0) {
        out[b * 2 + 0] = parts[0][0] + parts[1][0] + parts[2][0] + parts[3][0] + b2[0];
        out[b * 2 + 1] = parts[0][1] + parts[1][1] + parts[2][1] + parts[3][1] + b2[1];
    }
}

// ---------------- launch ----------------
extern "C" void kernel_launch(void* const* d_in, const int* in_sizes, int n_in,
                              void* d_out, int out_size, void* d_ws, size_t ws_size,
                              hipStream_t stream) {
    const float* x     = (const float*)d_in[0];
    const float* xda   = (const float*)d_in[1];
    const int*   ei    = (const int*)d_in[2];
    const int*   batch = (const int*)d_in[3];
    const int*   root  = (const int*)d_in[4];
    const float* td_w1 = (const float*)d_in[5];
    const float* td_b1 = (const float*)d_in[6];
    const float* td_w2 = (const float*)d_in[7];
    const float* td_b2 = (const float*)d_in[8];
    const float* bu_w1 = (const float*)d_in[9];
    const float* bu_b1 = (const float*)d_in[10];
    const float* bu_w2 = (const float*)d_in[11];
    const float* bu_b2 = (const float*)d_in[12];
    const float* mw1   = (const float*)d_in[13];
    const float* mb1   = (const float*)d_in[14];
    const float* mw2   = (const float*)d_in[15];
    const float* mb2   = (const float*)d_in[16];
    float* out = (float*)d_out;

    float* h       = (float*)d_ws;                         // NN*128
    float* agg     = h + (size_t)NN * 128;                 // NN*128
    float* dinv_td = agg + (size_t)NN * 128;               // NN
    float* dinv_bu = dinv_td + NN;                         // NN
    float* x2root  = dinv_bu + NN;                         // NB*128
    float* rootmix = x2root + (size_t)NB * 128;            // NB*128
    float* gbuf    = rootmix + (size_t)NB * 128;           // NB*512
    int*   deg_td  = (int*)(gbuf + (size_t)NB * 512);      // NN
    int*   deg_bu  = deg_td + NN;                          // NN
    int*   cnt     = deg_bu + NN;                          // NB
    int*   rp_td   = cnt + NB;                             // NN+1
    int*   rp_bu   = rp_td + NN + 1;                       // NN+1
    int*   cur_td  = rp_bu + NN + 1;                       // NN
    int*   cur_bu  = cur_td + NN;                          // NN
    int*   csr_td  = cur_bu + NN;                          // NE
    int*   csr_bu  = csr_td + NE;                          // NE

    hipMemsetAsync(deg_td, 0, (size_t)(2 * NN + NB) * sizeof(int), stream);
    hipMemsetAsync(gbuf, 0, (size_t)NB * 512 * sizeof(float), stream);

    deg_count_k<<<(NE + 255) / 256, 256, 0, stream>>>(ei, deg_td, deg_bu);
    count_nodes_k<<<(NN + 255) / 256, 256, 0, stream>>>(batch, cnt);
    make_dinv_k<<<(NN + 255) / 256, 256, 0, stream>>>(deg_td, deg_bu, dinv_td, dinv_bu);
    scan_k<<<2, 1024, 0, stream>>>(deg_td, deg_bu, rp_td, rp_bu, cur_td, cur_bu);
    csr_fill_k<<<(NE + 255) / 256, 256, 0, stream>>>(ei, cur_td, cur_bu, csr_td, csr_bu);

    auto run_branch = [&](const int* rp, const int* csr, const float* dinv,
                          const float* w1, const float* b1,
                          const float* w2, const float* b2, int boff) {
        gemm128_k<0><<<NN / 32, 256, 0, stream>>>(x, xda, nullptr, w1, nullptr, nullptr, dinv, h);
        gather_k<0><<<(NN + 7) / 8, 256, 0, stream>>>(rp, csr, dinv, h, b1, agg, nullptr, nullptr, 0);
        extract_root_k<<<NB, 128, 0, stream>>>(agg, root, x2root);
        rootmix_k<<<NB, 128, 0, stream>>>(x, xda, root, w2, rootmix);
        gemm128_k<1><<<NN / 32, 256, 0, stream>>>(nullptr, nullptr, agg, w2, rootmix, batch, dinv, h);
        gather_k<1><<<(NN + 7) / 8, 256, 0, stream>>>(rp, csr, dinv, h, b2, nullptr, batch, gbuf, boff);
        gfinalize_k<<<NB, 128, 0, stream>>>(gbuf, cnt, x2root, boff);
    };

    // g = concat([bu, td]): bu at offset 0, td at offset 256
    run_branch(rp_bu, csr_bu, dinv_bu, bu_w1, bu_b1, bu_w2, bu_b2, 0);
    run_branch(rp_td, csr_td, dinv_td, td_w1, td_b1, td_w2, td_b2, 256);

    mlp_k<<<NB, 256, 0, stream>>>(gbuf, mw1, mb1, mw2, mb2, out);
}

// Round 3
// 1715.584 us; speedup vs baseline: 6.8523x; 1.0578x over previous
//
#include <hip/hip_runtime.h>

#define NN 100000
#define NE 1600000
#define NB 500

typedef unsigned short ushortT;

__device__ inline ushortT f2bf(float f) {
    unsigned u = __float_as_uint(f);
    unsigned r = (u + 0x7FFF + ((u >> 16) & 1)) >> 16;   // RNE
    return (ushortT)r;
}
__device__ inline float4 bf4_to_f4(ushort4 u) {
    float4 f;
    f.x = __uint_as_float((unsigned)u.x << 16);
    f.y = __uint_as_float((unsigned)u.y << 16);
    f.z = __uint_as_float((unsigned)u.z << 16);
    f.w = __uint_as_float((unsigned)u.w << 16);
    return f;
}

// ---------------- degree / dinv / counts ----------------

__global__ void deg_count_k(const int* __restrict__ ei,
                            int* __restrict__ deg_td, int* __restrict__ deg_bu) {
    int e = blockIdx.x * 256 + threadIdx.x;
    if (e >= NE) return;
    atomicAdd(&deg_td[ei[NE + e]], 1);
    atomicAdd(&deg_bu[ei[e]], 1);
}

__global__ void make_dinv_k(const int* __restrict__ deg_td, const int* __restrict__ deg_bu,
                            float* __restrict__ dinv_td, float* __restrict__ dinv_bu) {
    int v = blockIdx.x * 256 + threadIdx.x;
    if (v >= NN) return;
    dinv_td[v] = 1.0f / sqrtf((float)(deg_td[v] + 1));
    dinv_bu[v] = 1.0f / sqrtf((float)(deg_bu[v] + 1));
}

__global__ void count_nodes_k(const int* __restrict__ batch, int* __restrict__ cnt) {
    int v = blockIdx.x * 256 + threadIdx.x;
    if (v >= NN) return;
    atomicAdd(&cnt[batch[v]], 1);
}

// ---------------- exclusive scan of deg -> rowptr (+ cursor copy) ----------------
__global__ __launch_bounds__(1024) void scan_k(
    const int* __restrict__ d0, const int* __restrict__ d1,
    int* __restrict__ r0, int* __restrict__ r1,
    int* __restrict__ c0, int* __restrict__ c1) {
    const int* deg = blockIdx.x ? d1 : d0;
    int* rp  = blockIdx.x ? r1 : r0;
    int* cur = blockIdx.x ? c1 : c0;
    __shared__ int sh[1024];
    __shared__ int carry;
    const int t = threadIdx.x;
    if (t == 0) carry = 0;
    __syncthreads();
    for (int base = 0; base < NN; base += 1024) {
        int i = base + t;
        int v = (i < NN) ? deg[i] : 0;
        sh[t] = v;
        __syncthreads();
#pragma unroll
        for (int off = 1; off < 1024; off <<= 1) {
            int add = (t >= off) ? sh[t - off] : 0;
            __syncthreads();
            sh[t] += add;
            __syncthreads();
        }
        int excl = sh[t] - v;
        int tot = sh[1023];
        if (i < NN) { int val = carry + excl; rp[i] = val; cur[i] = val; }
        __syncthreads();
        if (t == 0) carry += tot;
        __syncthreads();
    }
    if (t == 0) rp[NN] = carry;
}

__global__ void csr_fill_k(const int* __restrict__ ei,
                           int* __restrict__ cur_td, int* __restrict__ cur_bu,
                           int* __restrict__ csr_td, int* __restrict__ csr_bu) {
    int e = blockIdx.x * 256 + threadIdx.x;
    if (e >= NE) return;
    int a = ei[e], b = ei[NE + e];
    int p = atomicAdd(&cur_td[b], 1); csr_td[p] = a;
    int q = atomicAdd(&cur_bu[a], 1); csr_bu[q] = b;
}

// ---------------- GEMM: [N,128] @ [128,128], bf16 output pre-scaled by dinv ----------------
// MODE 0: A = concat(x[v], x_da[v]);            hsb = bf16((A@W) * dinv[v])
// MODE 1: A = relu(inA[v]);                     hsb = bf16((A@W + rootmix[batch[v]]) * dinv[v])
template <int MODE>
__global__ __launch_bounds__(256) void gemm128_k(
    const float* __restrict__ x, const float* __restrict__ xda,
    const float* __restrict__ inA,
    const float* __restrict__ W,
    const float* __restrict__ rootmix, const int* __restrict__ batch,
    const float* __restrict__ dinv,
    ushortT* __restrict__ hsb) {
    __shared__ float As[32][128];
    __shared__ float Ws[64][128];
    const int t = threadIdx.x;
    const int row0 = blockIdx.x * 32;

#pragma unroll
    for (int i = 0; i < 4; i++) {
        int idx = t + i * 256;
        int r = idx >> 5, c4 = idx & 31;
        int v = row0 + r;
        float4 a;
        if (MODE == 0) {
            a = (c4 < 24) ? ((const float4*)(x + (size_t)v * 96))[c4]
                          : ((const float4*)(xda + (size_t)v * 32))[c4 - 24];
        } else {
            a = ((const float4*)(inA + (size_t)v * 128))[c4];
            a.x = fmaxf(a.x, 0.f); a.y = fmaxf(a.y, 0.f);
            a.z = fmaxf(a.z, 0.f); a.w = fmaxf(a.w, 0.f);
        }
        *((float4*)&As[r][c4 * 4]) = a;
    }

    const int cg = (t & 31) * 4;
    const int rg = (t >> 5) * 4;
    float acc[4][4] = {};
    const float4* W4 = (const float4*)W;

    for (int kb = 0; kb < 2; kb++) {
        __syncthreads();
#pragma unroll
        for (int i = 0; i < 8; i++) {
            int idx = t + i * 256;
            ((float4*)Ws)[idx] = W4[kb * 2048 + idx];
        }
        __syncthreads();
#pragma unroll 4
        for (int k = 0; k < 64; k += 4) {
            const int kg = kb * 64 + k;
            float4 a0 = *(const float4*)&As[rg + 0][kg];
            float4 a1 = *(const float4*)&As[rg + 1][kg];
            float4 a2 = *(const float4*)&As[rg + 2][kg];
            float4 a3 = *(const float4*)&As[rg + 3][kg];
            float4 w0 = *(const float4*)&Ws[k + 0][cg];
            float4 w1 = *(const float4*)&Ws[k + 1][cg];
            float4 w2 = *(const float4*)&Ws[k + 2][cg];
            float4 w3 = *(const float4*)&Ws[k + 3][cg];
            float aa[4][4] = {{a0.x,a0.y,a0.z,a0.w},{a1.x,a1.y,a1.z,a1.w},
                              {a2.x,a2.y,a2.z,a2.w},{a3.x,a3.y,a3.z,a3.w}};
            float ww[4][4] = {{w0.x,w0.y,w0.z,w0.w},{w1.x,w1.y,w1.z,w1.w},
                              {w2.x,w2.y,w2.z,w2.w},{w3.x,w3.y,w3.z,w3.w}};
#pragma unroll
            for (int kk = 0; kk < 4; kk++)
#pragma unroll
                for (int i = 0; i < 4; i++)
#pragma unroll
                    for (int j = 0; j < 4; j++)
                        acc[i][j] = fmaf(aa[i][kk], ww[kk][j], acc[i][j]);
        }
    }

#pragma unroll
    for (int i = 0; i < 4; i++) {
        int v = row0 + rg + i;
        float dd = dinv[v];
        float4 o = make_float4(acc[i][0], acc[i][1], acc[i][2], acc[i][3]);
        if (MODE == 1) {
            float4 rm = ((const float4*)(rootmix + (size_t)batch[v] * 128))[cg >> 2];
            o.x += rm.x; o.y += rm.y; o.z += rm.z; o.w += rm.w;
        }
        ushort4 ub = make_ushort4(f2bf(o.x * dd), f2bf(o.y * dd), f2bf(o.z * dd), f2bf(o.w * dd));
        *((ushort4*)(hsb + (size_t)v * 128 + cg)) = ub;
    }
}

// ---------------- CSR gather: agg[v] = dinv[v]*(sum hs[nbr] + hs[v]) + bias ----------------
// MODE 0: store f32 row to agg.    MODE 1: relu row, atomicAdd into gbuf[batch[v]].
template <int MODE>
__global__ __launch_bounds__(256) void gather_k(
    const int* __restrict__ rowptr, const int* __restrict__ csr,
    const float* __restrict__ dinv, const ushortT* __restrict__ hsb,
    const float* __restrict__ bias,
    float* __restrict__ agg,
    const int* __restrict__ batch, float* __restrict__ gbuf, int boff) {
    int v = blockIdx.x * 8 + (threadIdx.x >> 5);
    if (v >= NN) return;
    const int lane = threadIdx.x & 31;
    int beg = rowptr[v], end = rowptr[v + 1];
    float4 acc = bf4_to_f4(((const ushort4*)(hsb + (size_t)v * 128))[lane]);  // self loop
    for (int base = beg; base < end; base += 32) {
        int n = end - base; if (n > 32) n = 32;
        int idx = (lane < n) ? csr[base + lane] : 0;   // pad with node 0 (stays cached)
        for (int i = 0; i < n; i += 8) {
            int rem = n - i;
            ushort4 u[8];
#pragma unroll
            for (int j = 0; j < 8; j++) {
                int s = __shfl(idx, i + j, 32);
                u[j] = ((const ushort4*)(hsb + (size_t)s * 128))[lane];
            }
#pragma unroll
            for (int j = 0; j < 8; j++) {
                if (j < rem) {
                    float4 f = bf4_to_f4(u[j]);
                    acc.x += f.x; acc.y += f.y; acc.z += f.z; acc.w += f.w;
                }
            }
        }
    }
    float dd = dinv[v];
    float4 b4 = ((const float4*)bias)[lane];
    float4 o;
    o.x = fmaf(acc.x, dd, b4.x); o.y = fmaf(acc.y, dd, b4.y);
    o.z = fmaf(acc.z, dd, b4.z); o.w = fmaf(acc.w, dd, b4.w);
    if (MODE == 0) {
        ((float4*)(agg + (size_t)v * 128))[lane] = o;
    } else {
        float* dst = gbuf + (size_t)batch[v] * 512 + boff + lane * 4;
        unsafeAtomicAdd(dst + 0, fmaxf(o.x, 0.f));
        unsafeAtomicAdd(dst + 1, fmaxf(o.y, 0.f));
        unsafeAtomicAdd(dst + 2, fmaxf(o.z, 0.f));
        unsafeAtomicAdd(dst + 3, fmaxf(o.w, 0.f));
    }
}

// ---------------- root helpers ----------------
__global__ void extract_root_k(const float* __restrict__ agg, const int* __restrict__ root,
                               float* __restrict__ x2root) {
    int b = blockIdx.x, t = threadIdx.x;
    x2root[(size_t)b * 128 + t] = agg[(size_t)root[b] * 128 + t];
}

__global__ void rootmix_k(const float* __restrict__ x, const float* __restrict__ xda,
                          const int* __restrict__ root, const float* __restrict__ W2,
                          float* __restrict__ rootmix) {
    __shared__ float xr[128];
    int b = blockIdx.x, t = threadIdx.x;
    int r = root[b];
    float val = (t < 96) ? x[(size_t)r * 96 + t] : xda[(size_t)r * 32 + (t - 96)];
    xr[t] = fmaxf(val, 0.f);
    __syncthreads();
    float acc = 0.f;
#pragma unroll 8
    for (int k = 0; k < 128; k++)
        acc = fmaf(xr[k], W2[(size_t)(128 + k) * 128 + t], acc);
    rootmix[(size_t)b * 128 + t] = acc;
}

__global__ void gfinalize_k(float* __restrict__ gbuf, const int* __restrict__ cnt,
                            const float* __restrict__ x2root, int boff) {
    int b = blockIdx.x, t = threadIdx.x;
    float c = (float)cnt[b];
    gbuf[(size_t)b * 512 + boff + t] /= c;
    gbuf[(size_t)b * 512 + boff + 128 + t] = x2root[(size_t)b * 128 + t];
}

// ---------------- final MLP ----------------
__global__ void mlp_k(const float* __restrict__ g, const float* __restrict__ w1,
                      const float* __restrict__ b1, const float* __restrict__ w2,
                      const float* __restrict__ b2, float* __restrict__ out) {
    __shared__ float gs[512];
    __shared__ float parts[4][2];
    int b = blockIdx.x, t = threadIdx.x;
    gs[t] = g[(size_t)b * 512 + t];
    gs[t + 256] = g[(size_t)b * 512 + 256 + t];
    __syncthreads();
    float acc = b1[t];
#pragma unroll 8
    for (int k = 0; k < 512; k++)
        acc = fmaf(gs[k], w1[(size_t)k * 256 + t], acc);
    float hv = fmaxf(acc, 0.f);
    float p0 = hv * w2[t * 2 + 0];
    float p1 = hv * w2[t * 2 + 1];
#pragma unroll
    for (int off = 32; off; off >>= 1) {
        p0 += __shfl_down(p0, off);
        p1 += __shfl_down(p1, off);
    }
    int w = t >> 6;
    if ((t & 63) == 0) { parts[w][0] = p0; parts[w][1] = p1; }
    __syncthreads();
    if (t == 0) {
        out[b * 2 + 0] = parts[0][0] + parts[1][0] + parts[2][0] + parts[3][0] + b2[0];
        out[b * 2 + 1] = parts[0][1] + parts[1][1] + parts[2][1] + parts[3][1] + b2[1];
    }
}

// ---------------- launch ----------------
extern "C" void kernel_launch(void* const* d_in, const int* in_sizes, int n_in,
                              void* d_out, int out_size, void* d_ws, size_t ws_size,
                              hipStream_t stream) {
    const float* x     = (const float*)d_in[0];
    const float* xda   = (const float*)d_in[1];
    const int*   ei    = (const int*)d_in[2];
    const int*   batch = (const int*)d_in[3];
    const int*   root  = (const int*)d_in[4];
    const float* td_w1 = (const float*)d_in[5];
    const float* td_b1 = (const float*)d_in[6];
    const float* td_w2 = (const float*)d_in[7];
    const float* td_b2 = (const float*)d_in[8];
    const float* bu_w1 = (const float*)d_in[9];
    const float* bu_b1 = (const float*)d_in[10];
    const float* bu_w2 = (const float*)d_in[11];
    const float* bu_b2 = (const float*)d_in[12];
    const float* mw1   = (const float*)d_in[13];
    const float* mb1   = (const float*)d_in[14];
    const float* mw2   = (const float*)d_in[15];
    const float* mb2   = (const float*)d_in[16];
    float* out = (float*)d_out;

    float*   agg     = (float*)d_ws;                       // NN*128 f32
    float*   dinv_td = agg + (size_t)NN * 128;             // NN
    float*   dinv_bu = dinv_td + NN;                       // NN
    float*   x2root  = dinv_bu + NN;                       // NB*128
    float*   rootmix = x2root + (size_t)NB * 128;          // NB*128
    float*   gbuf    = rootmix + (size_t)NB * 128;         // NB*512
    ushortT* hsb     = (ushortT*)(gbuf + (size_t)NB * 512);// NN*128 bf16
    int*     deg_td  = (int*)(hsb + (size_t)NN * 128);     // NN
    int*     deg_bu  = deg_td + NN;                        // NN
    int*     cnt     = deg_bu + NN;                        // NB
    int*     rp_td   = cnt + NB;                           // NN+1
    int*     rp_bu   = rp_td + NN + 1;                     // NN+1
    int*     cur_td  = rp_bu + NN + 1;                     // NN
    int*     cur_bu  = cur_td + NN;                        // NN
    int*     csr_td  = cur_bu + NN;                        // NE
    int*     csr_bu  = csr_td + NE;                        // NE

    hipMemsetAsync(deg_td, 0, (size_t)(2 * NN + NB) * sizeof(int), stream);
    hipMemsetAsync(gbuf, 0, (size_t)NB * 512 * sizeof(float), stream);

    deg_count_k<<<(NE + 255) / 256, 256, 0, stream>>>(ei, deg_td, deg_bu);
    count_nodes_k<<<(NN + 255) / 256, 256, 0, stream>>>(batch, cnt);
    make_dinv_k<<<(NN + 255) / 256, 256, 0, stream>>>(deg_td, deg_bu, dinv_td, dinv_bu);
    scan_k<<<2, 1024, 0, stream>>>(deg_td, deg_bu, rp_td, rp_bu, cur_td, cur_bu);
    csr_fill_k<<<(NE + 255) / 256, 256, 0, stream>>>(ei, cur_td, cur_bu, csr_td, csr_bu);

    auto run_branch = [&](const int* rp, const int* csr, const float* dinv,
                          const float* w1, const float* b1,
                          const float* w2, const float* b2, int boff) {
        gemm128_k<0><<<NN / 32, 256, 0, stream>>>(x, xda, nullptr, w1, nullptr, nullptr, dinv, hsb);
        gather_k<0><<<(NN + 7) / 8, 256, 0, stream>>>(rp, csr, dinv, hsb, b1, agg, nullptr, nullptr, 0);
        extract_root_k<<<NB, 128, 0, stream>>>(agg, root, x2root);
        rootmix_k<<<NB, 128, 0, stream>>>(x, xda, root, w2, rootmix);
        gemm128_k<1><<<NN / 32, 256, 0, stream>>>(nullptr, nullptr, agg, w2, rootmix, batch, dinv, hsb);
        gather_k<1><<<(NN + 7) / 8, 256, 0, stream>>>(rp, csr, dinv, hsb, b2, nullptr, batch, gbuf, boff);
        gfinalize_k<<<NB, 128, 0, stream>>>(gbuf, cnt, x2root, boff);
    };

    run_branch(rp_bu, csr_bu, dinv_bu, bu_w1, bu_b1, bu_w2, bu_b2, 0);
    run_branch(rp_td, csr_td, dinv_td, td_w1, td_b1, td_w2, td_b2, 256);

    mlp_k<<<NB, 256, 0, stream>>>(gbuf, mw1, mb1, mw2, mb2, out);
}

// Round 4
// 1188.264 us; speedup vs baseline: 9.8932x; 1.4438x over previous
//
#include <hip/hip_runtime.h>

#define NN 100000
#define NE 1600000
#define NB 500
#define NPG 200   // nodes per graph (batch = arange // 200, rootindex = b*200)

typedef unsigned short ushortT;

__device__ inline ushortT f2bf(float f) {
    unsigned u = __float_as_uint(f);
    return (ushortT)((u + 0x7FFF + ((u >> 16) & 1)) >> 16);   // RNE
}
__device__ inline float bf2f(ushortT u) { return __uint_as_float((unsigned)u << 16); }
__device__ inline float4 bf4_to_f4(ushort4 u) {
    return make_float4(bf2f(u.x), bf2f(u.y), bf2f(u.z), bf2f(u.w));
}

// ---------------- degree / dinv / counts ----------------

__global__ void deg_count_k(const int* __restrict__ ei,
                            int* __restrict__ deg_td, int* __restrict__ deg_bu) {
    int e = blockIdx.x * 256 + threadIdx.x;
    if (e >= NE) return;
    atomicAdd(&deg_td[ei[NE + e]], 1);
    atomicAdd(&deg_bu[ei[e]], 1);
}

__global__ void make_dinv_k(const int* __restrict__ deg_td, const int* __restrict__ deg_bu,
                            float* __restrict__ dinv_td, float* __restrict__ dinv_bu) {
    int v = blockIdx.x * 256 + threadIdx.x;
    if (v >= NN) return;
    dinv_td[v] = 1.0f / sqrtf((float)(deg_td[v] + 1));
    dinv_bu[v] = 1.0f / sqrtf((float)(deg_bu[v] + 1));
}

__global__ void count_nodes_k(const int* __restrict__ batch, int* __restrict__ cnt) {
    int v = blockIdx.x * 256 + threadIdx.x;
    if (v >= NN) return;
    atomicAdd(&cnt[batch[v]], 1);
}

// ---------------- exclusive scan of deg -> rowptr (+ cursor copy) ----------------
__global__ __launch_bounds__(1024) void scan_k(
    const int* __restrict__ d0, const int* __restrict__ d1,
    int* __restrict__ r0, int* __restrict__ r1,
    int* __restrict__ c0, int* __restrict__ c1) {
    const int* deg = blockIdx.x ? d1 : d0;
    int* rp  = blockIdx.x ? r1 : r0;
    int* cur = blockIdx.x ? c1 : c0;
    __shared__ int sh[1024];
    __shared__ int carry;
    const int t = threadIdx.x;
    if (t == 0) carry = 0;
    __syncthreads();
    for (int base = 0; base < NN; base += 1024) {
        int i = base + t;
        int v = (i < NN) ? deg[i] : 0;
        sh[t] = v;
        __syncthreads();
#pragma unroll
        for (int off = 1; off < 1024; off <<= 1) {
            int add = (t >= off) ? sh[t - off] : 0;
            __syncthreads();
            sh[t] += add;
            __syncthreads();
        }
        int excl = sh[t] - v;
        int tot = sh[1023];
        if (i < NN) { int val = carry + excl; rp[i] = val; cur[i] = val; }
        __syncthreads();
        if (t == 0) carry += tot;
        __syncthreads();
    }
    if (t == 0) rp[NN] = carry;
}

__global__ void csr_fill_k(const int* __restrict__ ei,
                           int* __restrict__ cur_td, int* __restrict__ cur_bu,
                           int* __restrict__ csr_td, int* __restrict__ csr_bu) {
    int e = blockIdx.x * 256 + threadIdx.x;
    if (e >= NE) return;
    int a = ei[e], b = ei[NE + e];
    int p = atomicAdd(&cur_td[b], 1); csr_td[p] = a;
    int q = atomicAdd(&cur_bu[a], 1); csr_bu[q] = b;
}

// ---------------- fused conv1 GEMM: A = concat(x,x_da); two weight sets ----------------
// hs_a = bf16((A@Wa)*dinv_a[v]),  hs_b = bf16((A@Wb)*dinv_b[v])
__global__ __launch_bounds__(256) void gemm1x_k(
    const float* __restrict__ x, const float* __restrict__ xda,
    const float* __restrict__ Wa, const float* __restrict__ Wb,
    const float* __restrict__ dinv_a, const float* __restrict__ dinv_b,
    ushortT* __restrict__ hs_a, ushortT* __restrict__ hs_b) {
    __shared__ float As[32][128];
    __shared__ float Ws[64][128];
    const int t = threadIdx.x;
    const int row0 = blockIdx.x * 32;

#pragma unroll
    for (int i = 0; i < 4; i++) {
        int idx = t + i * 256;
        int r = idx >> 5, c4 = idx & 31;
        int v = row0 + r;
        float4 a = (c4 < 24) ? ((const float4*)(x + (size_t)v * 96))[c4]
                             : ((const float4*)(xda + (size_t)v * 32))[c4 - 24];
        *((float4*)&As[r][c4 * 4]) = a;
    }

    const int cg = (t & 31) * 4;
    const int rg = (t >> 5) * 4;
    float acc[2][4][4] = {};

    for (int w = 0; w < 2; w++) {
        const float4* W4 = (const float4*)(w ? Wb : Wa);
        for (int kb = 0; kb < 2; kb++) {
            __syncthreads();
#pragma unroll
            for (int i = 0; i < 8; i++) {
                int idx = t + i * 256;
                ((float4*)Ws)[idx] = W4[kb * 2048 + idx];
            }
            __syncthreads();
#pragma unroll 4
            for (int k = 0; k < 64; k += 4) {
                const int kg = kb * 64 + k;
                float4 a0 = *(const float4*)&As[rg + 0][kg];
                float4 a1 = *(const float4*)&As[rg + 1][kg];
                float4 a2 = *(const float4*)&As[rg + 2][kg];
                float4 a3 = *(const float4*)&As[rg + 3][kg];
                float4 w0 = *(const float4*)&Ws[k + 0][cg];
                float4 w1 = *(const float4*)&Ws[k + 1][cg];
                float4 w2 = *(const float4*)&Ws[k + 2][cg];
                float4 w3 = *(const float4*)&Ws[k + 3][cg];
                float aa[4][4] = {{a0.x,a0.y,a0.z,a0.w},{a1.x,a1.y,a1.z,a1.w},
                                  {a2.x,a2.y,a2.z,a2.w},{a3.x,a3.y,a3.z,a3.w}};
                float ww[4][4] = {{w0.x,w0.y,w0.z,w0.w},{w1.x,w1.y,w1.z,w1.w},
                                  {w2.x,w2.y,w2.z,w2.w},{w3.x,w3.y,w3.z,w3.w}};
#pragma unroll
                for (int kk = 0; kk < 4; kk++)
#pragma unroll
                    for (int i = 0; i < 4; i++)
#pragma unroll
                        for (int j = 0; j < 4; j++)
                            acc[w][i][j] = fmaf(aa[i][kk], ww[kk][j], acc[w][i][j]);
            }
        }
    }

#pragma unroll
    for (int i = 0; i < 4; i++) {
        int v = row0 + rg + i;
        float da = dinv_a[v], db = dinv_b[v];
        ushort4 ua = make_ushort4(f2bf(acc[0][i][0] * da), f2bf(acc[0][i][1] * da),
                                  f2bf(acc[0][i][2] * da), f2bf(acc[0][i][3] * da));
        ushort4 ub = make_ushort4(f2bf(acc[1][i][0] * db), f2bf(acc[1][i][1] * db),
                                  f2bf(acc[1][i][2] * db), f2bf(acc[1][i][3] * db));
        *((ushort4*)(hs_a + (size_t)v * 128 + cg)) = ua;
        *((ushort4*)(hs_b + (size_t)v * 128 + cg)) = ub;
    }
}

// ---------------- conv2 GEMM (per branch): A = relu(bf16 agg) ----------------
// hs = bf16((A@W[:128] + rootmix[batch[v]]) * dinv[v])
__global__ __launch_bounds__(256) void gemm2bf_k(
    const ushortT* __restrict__ agg, const float* __restrict__ W,
    const float* __restrict__ rootmix, const int* __restrict__ batch,
    const float* __restrict__ dinv, ushortT* __restrict__ hs) {
    __shared__ float As[32][128];
    __shared__ float Ws[64][128];
    const int t = threadIdx.x;
    const int row0 = blockIdx.x * 32;

#pragma unroll
    for (int i = 0; i < 4; i++) {
        int idx = t + i * 256;
        int r = idx >> 5, c4 = idx & 31;
        int v = row0 + r;
        float4 a = bf4_to_f4(((const ushort4*)(agg + (size_t)v * 128))[c4]);
        a.x = fmaxf(a.x, 0.f); a.y = fmaxf(a.y, 0.f);
        a.z = fmaxf(a.z, 0.f); a.w = fmaxf(a.w, 0.f);
        *((float4*)&As[r][c4 * 4]) = a;
    }

    const int cg = (t & 31) * 4;
    const int rg = (t >> 5) * 4;
    float acc[4][4] = {};
    const float4* W4 = (const float4*)W;

    for (int kb = 0; kb < 2; kb++) {
        __syncthreads();
#pragma unroll
        for (int i = 0; i < 8; i++) {
            int idx = t + i * 256;
            ((float4*)Ws)[idx] = W4[kb * 2048 + idx];
        }
        __syncthreads();
#pragma unroll 4
        for (int k = 0; k < 64; k += 4) {
            const int kg = kb * 64 + k;
            float4 a0 = *(const float4*)&As[rg + 0][kg];
            float4 a1 = *(const float4*)&As[rg + 1][kg];
            float4 a2 = *(const float4*)&As[rg + 2][kg];
            float4 a3 = *(const float4*)&As[rg + 3][kg];
            float4 w0 = *(const float4*)&Ws[k + 0][cg];
            float4 w1 = *(const float4*)&Ws[k + 1][cg];
            float4 w2 = *(const float4*)&Ws[k + 2][cg];
            float4 w3 = *(const float4*)&Ws[k + 3][cg];
            float aa[4][4] = {{a0.x,a0.y,a0.z,a0.w},{a1.x,a1.y,a1.z,a1.w},
                              {a2.x,a2.y,a2.z,a2.w},{a3.x,a3.y,a3.z,a3.w}};
            float ww[4][4] = {{w0.x,w0.y,w0.z,w0.w},{w1.x,w1.y,w1.z,w1.w},
                              {w2.x,w2.y,w2.z,w2.w},{w3.x,w3.y,w3.z,w3.w}};
#pragma unroll
            for (int kk = 0; kk < 4; kk++)
#pragma unroll
                for (int i = 0; i < 4; i++)
#pragma unroll
                    for (int j = 0; j < 4; j++)
                        acc[i][j] = fmaf(aa[i][kk], ww[kk][j], acc[i][j]);
        }
    }

#pragma unroll
    for (int i = 0; i < 4; i++) {
        int v = row0 + rg + i;
        float dd = dinv[v];
        float4 rm = ((const float4*)(rootmix + (size_t)batch[v] * 128))[cg >> 2];
        ushort4 ub = make_ushort4(f2bf((acc[i][0] + rm.x) * dd), f2bf((acc[i][1] + rm.y) * dd),
                                  f2bf((acc[i][2] + rm.z) * dd), f2bf((acc[i][3] + rm.w) * dd));
        *((ushort4*)(hs + (size_t)v * 128 + cg)) = ub;
    }
}

// ---------------- fused dual-branch CSR gather ----------------
// out[v] = bf16( [relu] ( dinv[v]*(sum hs[nbr] + hs[v]) + bias ) ), both branches.
// Interleaved 8+8 load batches -> ~16 outstanding gathers per 32-lane group.
template <int MODE>   // 0: plain store (conv1 agg); 1: relu store (conv2 rows for mean)
__global__ __launch_bounds__(256) void gather2x_k(
    const int* __restrict__ rp_a, const int* __restrict__ csr_a,
    const float* __restrict__ dinv_a, const ushortT* __restrict__ hs_a,
    const float* __restrict__ bias_a,
    const int* __restrict__ rp_b, const int* __restrict__ csr_b,
    const float* __restrict__ dinv_b, const ushortT* __restrict__ hs_b,
    const float* __restrict__ bias_b,
    ushortT* __restrict__ out_a, ushortT* __restrict__ out_b) {
    int v = blockIdx.x * 8 + (threadIdx.x >> 5);
    if (v >= NN) return;
    const int lane = threadIdx.x & 31;
    int ba = rp_a[v], ea = rp_a[v + 1];
    int bb = rp_b[v], eb = rp_b[v + 1];
    float4 acc_a = bf4_to_f4(((const ushort4*)(hs_a + (size_t)v * 128))[lane]);  // self
    float4 acc_b = bf4_to_f4(((const ushort4*)(hs_b + (size_t)v * 128))[lane]);

    while (ba < ea || bb < eb) {
        int na = ea - ba; if (na > 32) na = 32; if (na < 0) na = 0;
        int nb = eb - bb; if (nb > 32) nb = 32; if (nb < 0) nb = 0;
        int ia = (lane < na) ? csr_a[ba + lane] : 0;   // pad with node 0 (hot in cache)
        int ib = (lane < nb) ? csr_b[bb + lane] : 0;
        for (int i = 0; i < 32; i += 8) {
            if (i >= na && i >= nb) break;
            ushort4 ua[8], ub[8];
            if (i < na) {
#pragma unroll
                for (int j = 0; j < 8; j++) {
                    int s = __shfl(ia, i + j, 32);
                    ua[j] = ((const ushort4*)(hs_a + (size_t)s * 128))[lane];
                }
            }
            if (i < nb) {
#pragma unroll
                for (int j = 0; j < 8; j++) {
                    int s = __shfl(ib, i + j, 32);
                    ub[j] = ((const ushort4*)(hs_b + (size_t)s * 128))[lane];
                }
            }
            if (i < na) {
#pragma unroll
                for (int j = 0; j < 8; j++)
                    if (i + j < na) {
                        float4 f = bf4_to_f4(ua[j]);
                        acc_a.x += f.x; acc_a.y += f.y; acc_a.z += f.z; acc_a.w += f.w;
                    }
            }
            if (i < nb) {
#pragma unroll
                for (int j = 0; j < 8; j++)
                    if (i + j < nb) {
                        float4 f = bf4_to_f4(ub[j]);
                        acc_b.x += f.x; acc_b.y += f.y; acc_b.z += f.z; acc_b.w += f.w;
                    }
            }
        }
        ba += 32; bb += 32;
    }

    float da = dinv_a[v], db = dinv_b[v];
    float4 pa = ((const float4*)bias_a)[lane];
    float4 pb = ((const float4*)bias_b)[lane];
    float4 oa = make_float4(fmaf(acc_a.x, da, pa.x), fmaf(acc_a.y, da, pa.y),
                            fmaf(acc_a.z, da, pa.z), fmaf(acc_a.w, da, pa.w));
    float4 ob = make_float4(fmaf(acc_b.x, db, pb.x), fmaf(acc_b.y, db, pb.y),
                            fmaf(acc_b.z, db, pb.z), fmaf(acc_b.w, db, pb.w));
    if (MODE == 1) {
        oa.x = fmaxf(oa.x, 0.f); oa.y = fmaxf(oa.y, 0.f); oa.z = fmaxf(oa.z, 0.f); oa.w = fmaxf(oa.w, 0.f);
        ob.x = fmaxf(ob.x, 0.f); ob.y = fmaxf(ob.y, 0.f); ob.z = fmaxf(ob.z, 0.f); ob.w = fmaxf(ob.w, 0.f);
    }
    ((ushort4*)(out_a + (size_t)v * 128))[lane] =
        make_ushort4(f2bf(oa.x), f2bf(oa.y), f2bf(oa.z), f2bf(oa.w));
    ((ushort4*)(out_b + (size_t)v * 128))[lane] =
        make_ushort4(f2bf(ob.x), f2bf(ob.y), f2bf(ob.z), f2bf(ob.w));
}

// ---------------- roots: x2root (bf16 agg -> f32) + rootmix, both branches ----------------
__global__ void roots_k(
    const float* __restrict__ x, const float* __restrict__ xda,
    const int* __restrict__ root,
    const ushortT* __restrict__ agg_a, const ushortT* __restrict__ agg_b,
    const float* __restrict__ W2a, const float* __restrict__ W2b,
    float* __restrict__ x2a, float* __restrict__ x2b,
    float* __restrict__ rma, float* __restrict__ rmb) {
    __shared__ float xr[128];
    int b = blockIdx.x, t = threadIdx.x;
    int r = root[b];
    if (t < 128) {
        float val = (t < 96) ? x[(size_t)r * 96 + t] : xda[(size_t)r * 32 + (t - 96)];
        xr[t] = fmaxf(val, 0.f);
    }
    __syncthreads();
    int br = t >> 7, c = t & 127;
    const ushortT* agg = br ? agg_b : agg_a;
    const float* W2 = br ? W2b : W2a;
    float* x2 = br ? x2b : x2a;
    float* rm = br ? rmb : rma;
    x2[(size_t)b * 128 + c] = bf2f(agg[(size_t)r * 128 + c]);
    float acc = 0.f;
#pragma unroll 8
    for (int k = 0; k < 128; k++)
        acc = fmaf(xr[k], W2[(size_t)(128 + k) * 128 + c], acc);
    rm[(size_t)b * 128 + c] = acc;
}

// ---------------- graph mean (contiguous segments, no atomics) ----------------
__global__ void gmean_k(const ushortT* __restrict__ ra, const ushortT* __restrict__ rb,
                        const int* __restrict__ cnt,
                        const float* __restrict__ x2a, const float* __restrict__ x2b,
                        float* __restrict__ gbuf) {
    int b = blockIdx.x, t = threadIdx.x;
    int br = t >> 7, c = t & 127;
    const ushortT* src = br ? rb : ra;
    size_t base = (size_t)b * NPG * 128 + c;
    float s = 0.f;
#pragma unroll 4
    for (int r = 0; r < NPG; r++)
        s += bf2f(src[base + (size_t)r * 128]);
    float inv = 1.0f / (float)cnt[b];
    const float* x2 = br ? x2b : x2a;
    int o = br ? 256 : 0;
    gbuf[(size_t)b * 512 + o + c] = s * inv;
    gbuf[(size_t)b * 512 + o + 128 + c] = x2[(size_t)b * 128 + c];
}

// ---------------- final MLP ----------------
__global__ void mlp_k(const float* __restrict__ g, const float* __restrict__ w1,
                      const float* __restrict__ b1, const float* __restrict__ w2,
                      const float* __restrict__ b2, float* __restrict__ out) {
    __shared__ float gs[512];
    __shared__ float parts[4][2];
    int b = blockIdx.x, t = threadIdx.x;
    gs[t] = g[(size_t)b * 512 + t];
    gs[t + 256] = g[(size_t)b * 512 + 256 + t];
    __syncthreads();
    float acc = b1[t];
#pragma unroll 8
    for (int k = 0; k < 512; k++)
        acc = fmaf(gs[k], w1[(size_t)k * 256 + t], acc);
    float hv = fmaxf(acc, 0.f);
    float p0 = hv * w2[t * 2 + 0];
    float p1 = hv * w2[t * 2 + 1];
#pragma unroll
    for (int off = 32; off; off >>= 1) {
        p0 += __shfl_down(p0, off);
        p1 += __shfl_down(p1, off);
    }
    int w = t >> 6;
    if ((t & 63) == 0) { parts[w][0] = p0; parts[w][1] = p1; }
    __syncthreads();
    if (t == 0) {
        out[b * 2 + 0] = parts[0][0] + parts[1][0] + parts[2][0] + parts[3][0] + b2[0];
        out[b * 2 + 1] = parts[0][1] + parts[1][1] + parts[2][1] + parts[3][1] + b2[1];
    }
}

// ---------------- launch ----------------
extern "C" void kernel_launch(void* const* d_in, const int* in_sizes, int n_in,
                              void* d_out, int out_size, void* d_ws, size_t ws_size,
                              hipStream_t stream) {
    const float* x     = (const float*)d_in[0];
    const float* xda   = (const float*)d_in[1];
    const int*   ei    = (const int*)d_in[2];
    const int*   batch = (const int*)d_in[3];
    const int*   root  = (const int*)d_in[4];
    const float* td_w1 = (const float*)d_in[5];
    const float* td_b1 = (const float*)d_in[6];
    const float* td_w2 = (const float*)d_in[7];
    const float* td_b2 = (const float*)d_in[8];
    const float* bu_w1 = (const float*)d_in[9];
    const float* bu_b1 = (const float*)d_in[10];
    const float* bu_w2 = (const float*)d_in[11];
    const float* bu_b2 = (const float*)d_in[12];
    const float* mw1   = (const float*)d_in[13];
    const float* mb1   = (const float*)d_in[14];
    const float* mw2   = (const float*)d_in[15];
    const float* mb2   = (const float*)d_in[16];
    float* out = (float*)d_out;

    // workspace layout (bf16 arrays first, then f32, then ints) — ~121 MB total
    ushortT* agg_bu  = (ushortT*)d_ws;                       // NN*128 bf16 (reused as relu rows)
    ushortT* agg_td  = agg_bu + (size_t)NN * 128;
    ushortT* hs_bu   = agg_td + (size_t)NN * 128;            // NN*128 bf16
    ushortT* hs_td   = hs_bu + (size_t)NN * 128;
    float*   dinv_td = (float*)(hs_td + (size_t)NN * 128);   // NN
    float*   dinv_bu = dinv_td + NN;                         // NN
    float*   x2_bu   = dinv_bu + NN;                         // NB*128
    float*   x2_td   = x2_bu + (size_t)NB * 128;
    float*   rm_bu   = x2_td + (size_t)NB * 128;             // NB*128
    float*   rm_td   = rm_bu + (size_t)NB * 128;
    float*   gbuf    = rm_td + (size_t)NB * 128;             // NB*512
    int*     deg_td  = (int*)(gbuf + (size_t)NB * 512);      // NN
    int*     deg_bu  = deg_td + NN;                          // NN
    int*     cnt     = deg_bu + NN;                          // NB
    int*     rp_td   = cnt + NB;                             // NN+1
    int*     rp_bu   = rp_td + NN + 1;                       // NN+1
    int*     cur_td  = rp_bu + NN + 1;                       // NN
    int*     cur_bu  = cur_td + NN;                          // NN
    int*     csr_td  = cur_bu + NN;                          // NE
    int*     csr_bu  = csr_td + NE;                          // NE

    hipMemsetAsync(deg_td, 0, (size_t)(2 * NN + NB) * sizeof(int), stream);

    deg_count_k<<<(NE + 255) / 256, 256, 0, stream>>>(ei, deg_td, deg_bu);
    count_nodes_k<<<(NN + 255) / 256, 256, 0, stream>>>(batch, cnt);
    make_dinv_k<<<(NN + 255) / 256, 256, 0, stream>>>(deg_td, deg_bu, dinv_td, dinv_bu);
    scan_k<<<2, 1024, 0, stream>>>(deg_td, deg_bu, rp_td, rp_bu, cur_td, cur_bu);
    csr_fill_k<<<(NE + 255) / 256, 256, 0, stream>>>(ei, cur_td, cur_bu, csr_td, csr_bu);

    // conv1 (both branches fused)
    gemm1x_k<<<NN / 32, 256, 0, stream>>>(x, xda, bu_w1, td_w1, dinv_bu, dinv_td, hs_bu, hs_td);
    gather2x_k<0><<<NN / 8, 256, 0, stream>>>(
        rp_bu, csr_bu, dinv_bu, hs_bu, bu_b1,
        rp_td, csr_td, dinv_td, hs_td, td_b1, agg_bu, agg_td);

    roots_k<<<NB, 256, 0, stream>>>(x, xda, root, agg_bu, agg_td, bu_w2, td_w2,
                                    x2_bu, x2_td, rm_bu, rm_td);

    // conv2
    gemm2bf_k<<<NN / 32, 256, 0, stream>>>(agg_bu, bu_w2, rm_bu, batch, dinv_bu, hs_bu);
    gemm2bf_k<<<NN / 32, 256, 0, stream>>>(agg_td, td_w2, rm_td, batch, dinv_td, hs_td);
    gather2x_k<1><<<NN / 8, 256, 0, stream>>>(
        rp_bu, csr_bu, dinv_bu, hs_bu, bu_b2,
        rp_td, csr_td, dinv_td, hs_td, td_b2, agg_bu, agg_td);   // relu rows over agg (dead)

    gmean_k<<<NB, 256, 0, stream>>>(agg_bu, agg_td, cnt, x2_bu, x2_td, gbuf);
    mlp_k<<<NB, 256, 0, stream>>>(gbuf, mw1, mb1, mw2, mb2, out);
}

// Round 5
// 682.747 us; speedup vs baseline: 17.2182x; 1.7404x over previous
//
#include <hip/hip_runtime.h>

#define NN 100000
#define NE 1600000
#define NB 500
#define NPG 200            // nodes per graph (batch = arange // 200)
#define BS 128             // nodes per bucket
#define NBUK 782           // ceil(NN / BS)
#define EPB 8192           // edges per block in hist/stage
#define NEB 196            // ceil(NE / EPB)

typedef unsigned short ushortT;

__device__ inline ushortT f2bf(float f) {
    unsigned u = __float_as_uint(f);
    return (ushortT)((u + 0x7FFF + ((u >> 16) & 1)) >> 16);   // RNE
}
__device__ inline float bf2f(ushortT u) { return __uint_as_float((unsigned)u << 16); }
__device__ inline float4 bf4_to_f4(ushort4 u) {
    return make_float4(bf2f(u.x), bf2f(u.y), bf2f(u.z), bf2f(u.w));
}

// ---------------- bucket histogram (both directions) ----------------
__global__ __launch_bounds__(512) void hist_k(const int* __restrict__ ei,
                                              int* __restrict__ bcnt_td,
                                              int* __restrict__ bcnt_bu) {
    __shared__ int h0[NBUK], h1[NBUK];
    const int t = threadIdx.x;
    for (int i = t; i < NBUK; i += 512) { h0[i] = 0; h1[i] = 0; }
    __syncthreads();
    int base = blockIdx.x * EPB;
#pragma unroll
    for (int j = 0; j < EPB / 512; j++) {
        int e = base + t + j * 512;
        if (e < NE) {
            int a = ei[e], b = ei[NE + e];
            atomicAdd(&h0[b >> 7], 1);   // td grouped by dst=b
            atomicAdd(&h1[a >> 7], 1);   // bu grouped by dst=a
        }
    }
    __syncthreads();
    for (int i = t; i < NBUK; i += 512) {
        if (h0[i]) atomicAdd(&bcnt_td[i], h0[i]);
        if (h1[i]) atomicAdd(&bcnt_bu[i], h1[i]);
    }
}

// ---------------- bucket scan: bcnt -> bbase (exclusive) + bcur copy ----------------
__global__ __launch_bounds__(1024) void bscan_k(
    const int* __restrict__ c0, const int* __restrict__ c1,
    int* __restrict__ b0, int* __restrict__ b1,
    int* __restrict__ q0, int* __restrict__ q1) {
    const int* c = blockIdx.x ? c1 : c0;
    int* bb = blockIdx.x ? b1 : b0;
    int* bq = blockIdx.x ? q1 : q0;
    __shared__ int sh[1024];
    const int t = threadIdx.x;
    int v = (t < NBUK) ? c[t] : 0;
    sh[t] = v;
    __syncthreads();
#pragma unroll
    for (int off = 1; off < 1024; off <<= 1) {
        int add = (t >= off) ? sh[t - off] : 0;
        __syncthreads();
        sh[t] += add;
        __syncthreads();
    }
    int excl = sh[t] - v;
    if (t < NBUK) { bb[t] = excl; bq[t] = excl; }
    if (t == NBUK - 1) bb[NBUK] = sh[t];
}

// ---------------- stage: scatter packed (val<<7 | key&127) grouped by key-bucket ----------
__global__ __launch_bounds__(512) void stage_k(const int* __restrict__ ei,
                                               int* __restrict__ bcur,
                                               int* __restrict__ stage, int dir) {
    __shared__ int hb[NBUK];
    const int t = threadIdx.x;
    for (int i = t; i < NBUK; i += 512) hb[i] = 0;
    __syncthreads();
    int base = blockIdx.x * EPB;
    int key[EPB / 512], val[EPB / 512];
#pragma unroll
    for (int j = 0; j < EPB / 512; j++) {
        int e = base + t + j * 512;
        key[j] = -1;
        if (e < NE) {
            int a = ei[e], b = ei[NE + e];
            key[j] = dir ? a : b;
            val[j] = dir ? b : a;
            atomicAdd(&hb[key[j] >> 7], 1);
        }
    }
    __syncthreads();
    for (int i = t; i < NBUK; i += 512) {
        int cc = hb[i];
        if (cc) hb[i] = atomicAdd(&bcur[i], cc);   // reserve global range; hb becomes cursor
    }
    __syncthreads();
#pragma unroll
    for (int j = 0; j < EPB / 512; j++) {
        if (key[j] >= 0) {
            int off = atomicAdd(&hb[key[j] >> 7], 1);
            stage[off] = (val[j] << 7) | (key[j] & 127);
        }
    }
}

// ---------------- place: per bucket, LDS node-histogram+scan -> rowptr, dinv, csr ----------
__global__ __launch_bounds__(256) void place_k(const int* __restrict__ stage,
                                               const int* __restrict__ bbase,
                                               int* __restrict__ rp, int* __restrict__ csr,
                                               float* __restrict__ dinv) {
    const int bucket = blockIdx.x;
    const int beg = bbase[bucket], end = bbase[bucket + 1];
    const int node0 = bucket << 7;
    __shared__ int lcnt[BS], lsc[BS], lcur[BS];
    const int t = threadIdx.x;
    if (t < BS) lcnt[t] = 0;
    __syncthreads();
    for (int i = beg + t; i < end; i += 256) atomicAdd(&lcnt[stage[i] & 127], 1);
    __syncthreads();
    if (t < BS) lsc[t] = lcnt[t];
    __syncthreads();
#pragma unroll
    for (int off = 1; off < BS; off <<= 1) {
        int add = (t < BS && t >= off) ? lsc[t - off] : 0;
        __syncthreads();
        if (t < BS) lsc[t] += add;
        __syncthreads();
    }
    if (t < BS) {
        int excl = lsc[t] - lcnt[t];
        lcur[t] = beg + excl;
        int node = node0 + t;
        if (node < NN) {
            rp[node] = beg + excl;
            dinv[node] = rsqrtf((float)(lcnt[t] + 1));
        }
    }
    if (bucket == NBUK - 1 && t == 0) rp[NN] = end;
    __syncthreads();
    for (int i = beg + t; i < end; i += 256) {
        int s = stage[i];
        int off = atomicAdd(&lcur[s & 127], 1);
        csr[off] = (int)((unsigned)s >> 7);
    }
}

// ---------------- counts per graph ----------------
__global__ void count_nodes_k(const int* __restrict__ batch, int* __restrict__ cnt) {
    int v = blockIdx.x * 256 + threadIdx.x;
    if (v >= NN) return;
    atomicAdd(&cnt[batch[v]], 1);
}

// ---------------- fused conv1 GEMM: A = concat(x,x_da); two weight sets ----------------
__global__ __launch_bounds__(256) void gemm1x_k(
    const float* __restrict__ x, const float* __restrict__ xda,
    const float* __restrict__ Wa, const float* __restrict__ Wb,
    const float* __restrict__ dinv_a, const float* __restrict__ dinv_b,
    ushortT* __restrict__ hs_a, ushortT* __restrict__ hs_b) {
    __shared__ float As[32][128];
    __shared__ float Ws[64][128];
    const int t = threadIdx.x;
    const int row0 = blockIdx.x * 32;

#pragma unroll
    for (int i = 0; i < 4; i++) {
        int idx = t + i * 256;
        int r = idx >> 5, c4 = idx & 31;
        int v = row0 + r;
        float4 a = (c4 < 24) ? ((const float4*)(x + (size_t)v * 96))[c4]
                             : ((const float4*)(xda + (size_t)v * 32))[c4 - 24];
        *((float4*)&As[r][c4 * 4]) = a;
    }

    const int cg = (t & 31) * 4;
    const int rg = (t >> 5) * 4;
    float acc[2][4][4] = {};

    for (int w = 0; w < 2; w++) {
        const float4* W4 = (const float4*)(w ? Wb : Wa);
        for (int kb = 0; kb < 2; kb++) {
            __syncthreads();
#pragma unroll
            for (int i = 0; i < 8; i++) {
                int idx = t + i * 256;
                ((float4*)Ws)[idx] = W4[kb * 2048 + idx];
            }
            __syncthreads();
#pragma unroll 4
            for (int k = 0; k < 64; k += 4) {
                const int kg = kb * 64 + k;
                float4 a0 = *(const float4*)&As[rg + 0][kg];
                float4 a1 = *(const float4*)&As[rg + 1][kg];
                float4 a2 = *(const float4*)&As[rg + 2][kg];
                float4 a3 = *(const float4*)&As[rg + 3][kg];
                float4 w0 = *(const float4*)&Ws[k + 0][cg];
                float4 w1 = *(const float4*)&Ws[k + 1][cg];
                float4 w2 = *(const float4*)&Ws[k + 2][cg];
                float4 w3 = *(const float4*)&Ws[k + 3][cg];
                float aa[4][4] = {{a0.x,a0.y,a0.z,a0.w},{a1.x,a1.y,a1.z,a1.w},
                                  {a2.x,a2.y,a2.z,a2.w},{a3.x,a3.y,a3.z,a3.w}};
                float ww[4][4] = {{w0.x,w0.y,w0.z,w0.w},{w1.x,w1.y,w1.z,w1.w},
                                  {w2.x,w2.y,w2.z,w2.w},{w3.x,w3.y,w3.z,w3.w}};
#pragma unroll
                for (int kk = 0; kk < 4; kk++)
#pragma unroll
                    for (int i = 0; i < 4; i++)
#pragma unroll
                        for (int j = 0; j < 4; j++)
                            acc[w][i][j] = fmaf(aa[i][kk], ww[kk][j], acc[w][i][j]);
            }
        }
    }

#pragma unroll
    for (int i = 0; i < 4; i++) {
        int v = row0 + rg + i;
        float da = dinv_a[v], db = dinv_b[v];
        ushort4 ua = make_ushort4(f2bf(acc[0][i][0] * da), f2bf(acc[0][i][1] * da),
                                  f2bf(acc[0][i][2] * da), f2bf(acc[0][i][3] * da));
        ushort4 ub = make_ushort4(f2bf(acc[1][i][0] * db), f2bf(acc[1][i][1] * db),
                                  f2bf(acc[1][i][2] * db), f2bf(acc[1][i][3] * db));
        *((ushort4*)(hs_a + (size_t)v * 128 + cg)) = ua;
        *((ushort4*)(hs_b + (size_t)v * 128 + cg)) = ub;
    }
}

// ---------------- conv2 GEMM (per branch): A = relu(bf16 agg) ----------------
__global__ __launch_bounds__(256) void gemm2bf_k(
    const ushortT* __restrict__ agg, const float* __restrict__ W,
    const float* __restrict__ rootmix, const int* __restrict__ batch,
    const float* __restrict__ dinv, ushortT* __restrict__ hs) {
    __shared__ float As[32][128];
    __shared__ float Ws[64][128];
    const int t = threadIdx.x;
    const int row0 = blockIdx.x * 32;

#pragma unroll
    for (int i = 0; i < 4; i++) {
        int idx = t + i * 256;
        int r = idx >> 5, c4 = idx & 31;
        int v = row0 + r;
        float4 a = bf4_to_f4(((const ushort4*)(agg + (size_t)v * 128))[c4]);
        a.x = fmaxf(a.x, 0.f); a.y = fmaxf(a.y, 0.f);
        a.z = fmaxf(a.z, 0.f); a.w = fmaxf(a.w, 0.f);
        *((float4*)&As[r][c4 * 4]) = a;
    }

    const int cg = (t & 31) * 4;
    const int rg = (t >> 5) * 4;
    float acc[4][4] = {};
    const float4* W4 = (const float4*)W;

    for (int kb = 0; kb < 2; kb++) {
        __syncthreads();
#pragma unroll
        for (int i = 0; i < 8; i++) {
            int idx = t + i * 256;
            ((float4*)Ws)[idx] = W4[kb * 2048 + idx];
        }
        __syncthreads();
#pragma unroll 4
        for (int k = 0; k < 64; k += 4) {
            const int kg = kb * 64 + k;
            float4 a0 = *(const float4*)&As[rg + 0][kg];
            float4 a1 = *(const float4*)&As[rg + 1][kg];
            float4 a2 = *(const float4*)&As[rg + 2][kg];
            float4 a3 = *(const float4*)&As[rg + 3][kg];
            float4 w0 = *(const float4*)&Ws[k + 0][cg];
            float4 w1 = *(const float4*)&Ws[k + 1][cg];
            float4 w2 = *(const float4*)&Ws[k + 2][cg];
            float4 w3 = *(const float4*)&Ws[k + 3][cg];
            float aa[4][4] = {{a0.x,a0.y,a0.z,a0.w},{a1.x,a1.y,a1.z,a1.w},
                              {a2.x,a2.y,a2.z,a2.w},{a3.x,a3.y,a3.z,a3.w}};
            float ww[4][4] = {{w0.x,w0.y,w0.z,w0.w},{w1.x,w1.y,w1.z,w1.w},
                              {w2.x,w2.y,w2.z,w2.w},{w3.x,w3.y,w3.z,w3.w}};
#pragma unroll
            for (int kk = 0; kk < 4; kk++)
#pragma unroll
                for (int i = 0; i < 4; i++)
#pragma unroll
                    for (int j = 0; j < 4; j++)
                        acc[i][j] = fmaf(aa[i][kk], ww[kk][j], acc[i][j]);
        }
    }

#pragma unroll
    for (int i = 0; i < 4; i++) {
        int v = row0 + rg + i;
        float dd = dinv[v];
        float4 rm = ((const float4*)(rootmix + (size_t)batch[v] * 128))[cg >> 2];
        ushort4 ub = make_ushort4(f2bf((acc[i][0] + rm.x) * dd), f2bf((acc[i][1] + rm.y) * dd),
                                  f2bf((acc[i][2] + rm.z) * dd), f2bf((acc[i][3] + rm.w) * dd));
        *((ushort4*)(hs + (size_t)v * 128 + cg)) = ub;
    }
}

// ---------------- fused dual-branch CSR gather ----------------
template <int MODE>   // 0: plain store (conv1 agg); 1: relu store (conv2 rows for mean)
__global__ __launch_bounds__(256) void gather2x_k(
    const int* __restrict__ rp_a, const int* __restrict__ csr_a,
    const float* __restrict__ dinv_a, const ushortT* __restrict__ hs_a,
    const float* __restrict__ bias_a,
    const int* __restrict__ rp_b, const int* __restrict__ csr_b,
    const float* __restrict__ dinv_b, const ushortT* __restrict__ hs_b,
    const float* __restrict__ bias_b,
    ushortT* __restrict__ out_a, ushortT* __restrict__ out_b) {
    int v = blockIdx.x * 8 + (threadIdx.x >> 5);
    if (v >= NN) return;
    const int lane = threadIdx.x & 31;
    int ba = rp_a[v], ea = rp_a[v + 1];
    int bb = rp_b[v], eb = rp_b[v + 1];
    float4 acc_a = bf4_to_f4(((const ushort4*)(hs_a + (size_t)v * 128))[lane]);  // self
    float4 acc_b = bf4_to_f4(((const ushort4*)(hs_b + (size_t)v * 128))[lane]);

    while (ba < ea || bb < eb) {
        int na = ea - ba; if (na > 32) na = 32; if (na < 0) na = 0;
        int nb = eb - bb; if (nb > 32) nb = 32; if (nb < 0) nb = 0;
        int ia = (lane < na) ? csr_a[ba + lane] : 0;
        int ib = (lane < nb) ? csr_b[bb + lane] : 0;
        for (int i = 0; i < 32; i += 8) {
            if (i >= na && i >= nb) break;
            ushort4 ua[8], ub[8];
            if (i < na) {
#pragma unroll
                for (int j = 0; j < 8; j++) {
                    int s = __shfl(ia, i + j, 32);
                    ua[j] = ((const ushort4*)(hs_a + (size_t)s * 128))[lane];
                }
            }
            if (i < nb) {
#pragma unroll
                for (int j = 0; j < 8; j++) {
                    int s = __shfl(ib, i + j, 32);
                    ub[j] = ((const ushort4*)(hs_b + (size_t)s * 128))[lane];
                }
            }
            if (i < na) {
#pragma unroll
                for (int j = 0; j < 8; j++)
                    if (i + j < na) {
                        float4 f = bf4_to_f4(ua[j]);
                        acc_a.x += f.x; acc_a.y += f.y; acc_a.z += f.z; acc_a.w += f.w;
                    }
            }
            if (i < nb) {
#pragma unroll
                for (int j = 0; j < 8; j++)
                    if (i + j < nb) {
                        float4 f = bf4_to_f4(ub[j]);
                        acc_b.x += f.x; acc_b.y += f.y; acc_b.z += f.z; acc_b.w += f.w;
                    }
            }
        }
        ba += 32; bb += 32;
    }

    float da = dinv_a[v], db = dinv_b[v];
    float4 pa = ((const float4*)bias_a)[lane];
    float4 pb = ((const float4*)bias_b)[lane];
    float4 oa = make_float4(fmaf(acc_a.x, da, pa.x), fmaf(acc_a.y, da, pa.y),
                            fmaf(acc_a.z, da, pa.z), fmaf(acc_a.w, da, pa.w));
    float4 ob = make_float4(fmaf(acc_b.x, db, pb.x), fmaf(acc_b.y, db, pb.y),
                            fmaf(acc_b.z, db, pb.z), fmaf(acc_b.w, db, pb.w));
    if (MODE == 1) {
        oa.x = fmaxf(oa.x, 0.f); oa.y = fmaxf(oa.y, 0.f); oa.z = fmaxf(oa.z, 0.f); oa.w = fmaxf(oa.w, 0.f);
        ob.x = fmaxf(ob.x, 0.f); ob.y = fmaxf(ob.y, 0.f); ob.z = fmaxf(ob.z, 0.f); ob.w = fmaxf(ob.w, 0.f);
    }
    ((ushort4*)(out_a + (size_t)v * 128))[lane] =
        make_ushort4(f2bf(oa.x), f2bf(oa.y), f2bf(oa.z), f2bf(oa.w));
    ((ushort4*)(out_b + (size_t)v * 128))[lane] =
        make_ushort4(f2bf(ob.x), f2bf(ob.y), f2bf(ob.z), f2bf(ob.w));
}

// ---------------- roots: x2root + rootmix, both branches ----------------
__global__ void roots_k(
    const float* __restrict__ x, const float* __restrict__ xda,
    const int* __restrict__ root,
    const ushortT* __restrict__ agg_a, const ushortT* __restrict__ agg_b,
    const float* __restrict__ W2a, const float* __restrict__ W2b,
    float* __restrict__ x2a, float* __restrict__ x2b,
    float* __restrict__ rma, float* __restrict__ rmb) {
    __shared__ float xr[128];
    int b = blockIdx.x, t = threadIdx.x;
    int r = root[b];
    if (t < 128) {
        float val = (t < 96) ? x[(size_t)r * 96 + t] : xda[(size_t)r * 32 + (t - 96)];
        xr[t] = fmaxf(val, 0.f);
    }
    __syncthreads();
    int br = t >> 7, c = t & 127;
    const ushortT* agg = br ? agg_b : agg_a;
    const float* W2 = br ? W2b : W2a;
    float* x2 = br ? x2b : x2a;
    float* rm = br ? rmb : rma;
    x2[(size_t)b * 128 + c] = bf2f(agg[(size_t)r * 128 + c]);
    float acc = 0.f;
#pragma unroll 8
    for (int k = 0; k < 128; k++)
        acc = fmaf(xr[k], W2[(size_t)(128 + k) * 128 + c], acc);
    rm[(size_t)b * 128 + c] = acc;
}

// ---------------- graph mean (contiguous segments) ----------------
__global__ void gmean_k(const ushortT* __restrict__ ra, const ushortT* __restrict__ rb,
                        const int* __restrict__ cnt,
                        const float* __restrict__ x2a, const float* __restrict__ x2b,
                        float* __restrict__ gbuf) {
    int b = blockIdx.x, t = threadIdx.x;
    int br = t >> 7, c = t & 127;
    const ushortT* src = br ? rb : ra;
    size_t base = (size_t)b * NPG * 128 + c;
    float s = 0.f;
#pragma unroll 4
    for (int r = 0; r < NPG; r++)
        s += bf2f(src[base + (size_t)r * 128]);
    float inv = 1.0f / (float)cnt[b];
    const float* x2 = br ? x2b : x2a;
    int o = br ? 256 : 0;
    gbuf[(size_t)b * 512 + o + c] = s * inv;
    gbuf[(size_t)b * 512 + o + 128 + c] = x2[(size_t)b * 128 + c];
}

// ---------------- final MLP ----------------
__global__ void mlp_k(const float* __restrict__ g, const float* __restrict__ w1,
                      const float* __restrict__ b1, const float* __restrict__ w2,
                      const float* __restrict__ b2, float* __restrict__ out) {
    __shared__ float gs[512];
    __shared__ float parts[4][2];
    int b = blockIdx.x, t = threadIdx.x;
    gs[t] = g[(size_t)b * 512 + t];
    gs[t + 256] = g[(size_t)b * 512 + 256 + t];
    __syncthreads();
    float acc = b1[t];
#pragma unroll 8
    for (int k = 0; k < 512; k++)
        acc = fmaf(gs[k], w1[(size_t)k * 256 + t], acc);
    float hv = fmaxf(acc, 0.f);
    float p0 = hv * w2[t * 2 + 0];
    float p1 = hv * w2[t * 2 + 1];
#pragma unroll
    for (int off = 32; off; off >>= 1) {
        p0 += __shfl_down(p0, off);
        p1 += __shfl_down(p1, off);
    }
    int w = t >> 6;
    if ((t & 63) == 0) { parts[w][0] = p0; parts[w][1] = p1; }
    __syncthreads();
    if (t == 0) {
        out[b * 2 + 0] = parts[0][0] + parts[1][0] + parts[2][0] + parts[3][0] + b2[0];
        out[b * 2 + 1] = parts[0][1] + parts[1][1] + parts[2][1] + parts[3][1] + b2[1];
    }
}

// ---------------- launch ----------------
extern "C" void kernel_launch(void* const* d_in, const int* in_sizes, int n_in,
                              void* d_out, int out_size, void* d_ws, size_t ws_size,
                              hipStream_t stream) {
    const float* x     = (const float*)d_in[0];
    const float* xda   = (const float*)d_in[1];
    const int*   ei    = (const int*)d_in[2];
    const int*   batch = (const int*)d_in[3];
    const int*   root  = (const int*)d_in[4];
    const float* td_w1 = (const float*)d_in[5];
    const float* td_b1 = (const float*)d_in[6];
    const float* td_w2 = (const float*)d_in[7];
    const float* td_b2 = (const float*)d_in[8];
    const float* bu_w1 = (const float*)d_in[9];
    const float* bu_b1 = (const float*)d_in[10];
    const float* bu_w2 = (const float*)d_in[11];
    const float* bu_b2 = (const float*)d_in[12];
    const float* mw1   = (const float*)d_in[13];
    const float* mb1   = (const float*)d_in[14];
    const float* mw2   = (const float*)d_in[15];
    const float* mb2   = (const float*)d_in[16];
    float* out = (float*)d_out;

    // workspace layout
    ushortT* agg_bu  = (ushortT*)d_ws;                       // NN*128 bf16 (dead during preproc)
    ushortT* agg_td  = agg_bu + (size_t)NN * 128;
    ushortT* hs_bu   = agg_td + (size_t)NN * 128;
    ushortT* hs_td   = hs_bu + (size_t)NN * 128;
    float*   dinv_td = (float*)(hs_td + (size_t)NN * 128);   // NN
    float*   dinv_bu = dinv_td + NN;                         // NN
    float*   x2_bu   = dinv_bu + NN;                         // NB*128
    float*   x2_td   = x2_bu + (size_t)NB * 128;
    float*   rm_bu   = x2_td + (size_t)NB * 128;             // NB*128
    float*   rm_td   = rm_bu + (size_t)NB * 128;
    float*   gbuf    = rm_td + (size_t)NB * 128;             // NB*512
    int*     cnt     = (int*)(gbuf + (size_t)NB * 512);      // NB
    int*     bcnt_td = cnt + NB;                             // NBUK
    int*     bcnt_bu = bcnt_td + NBUK;                       // NBUK
    int*     bbase_td= bcnt_bu + NBUK;                       // NBUK+1
    int*     bbase_bu= bbase_td + NBUK + 1;                  // NBUK+1
    int*     bcur_td = bbase_bu + NBUK + 1;                  // NBUK
    int*     bcur_bu = bcur_td + NBUK;                       // NBUK
    int*     rp_td   = bcur_bu + NBUK;                       // NN+1
    int*     rp_bu   = rp_td + NN + 1;                       // NN+1
    int*     csr_td  = rp_bu + NN + 1;                       // NE
    int*     csr_bu  = csr_td + NE;                          // NE
    int*     stage   = (int*)agg_bu;                         // NE ints, aliases agg_bu (dead)

    hipMemsetAsync(cnt, 0, (size_t)(NB + 2 * NBUK) * sizeof(int), stream);

    // CSR build: hist -> bucket scan -> (stage -> place) x 2 directions
    hist_k<<<NEB, 512, 0, stream>>>(ei, bcnt_td, bcnt_bu);
    count_nodes_k<<<(NN + 255) / 256, 256, 0, stream>>>(batch, cnt);
    bscan_k<<<2, 1024, 0, stream>>>(bcnt_td, bcnt_bu, bbase_td, bbase_bu, bcur_td, bcur_bu);
    stage_k<<<NEB, 512, 0, stream>>>(ei, bcur_td, stage, 0);
    place_k<<<NBUK, 256, 0, stream>>>(stage, bbase_td, rp_td, csr_td, dinv_td);
    stage_k<<<NEB, 512, 0, stream>>>(ei, bcur_bu, stage, 1);
    place_k<<<NBUK, 256, 0, stream>>>(stage, bbase_bu, rp_bu, csr_bu, dinv_bu);

    // conv1 (both branches fused)
    gemm1x_k<<<NN / 32, 256, 0, stream>>>(x, xda, bu_w1, td_w1, dinv_bu, dinv_td, hs_bu, hs_td);
    gather2x_k<0><<<NN / 8, 256, 0, stream>>>(
        rp_bu, csr_bu, dinv_bu, hs_bu, bu_b1,
        rp_td, csr_td, dinv_td, hs_td, td_b1, agg_bu, agg_td);

    roots_k<<<NB, 256, 0, stream>>>(x, xda, root, agg_bu, agg_td, bu_w2, td_w2,
                                    x2_bu, x2_td, rm_bu, rm_td);

    // conv2
    gemm2bf_k<<<NN / 32, 256, 0, stream>>>(agg_bu, bu_w2, rm_bu, batch, dinv_bu, hs_bu);
    gemm2bf_k<<<NN / 32, 256, 0, stream>>>(agg_td, td_w2, rm_td, batch, dinv_td, hs_td);
    gather2x_k<1><<<NN / 8, 256, 0, stream>>>(
        rp_bu, csr_bu, dinv_bu, hs_bu, bu_b2,
        rp_td, csr_td, dinv_td, hs_td, td_b2, agg_bu, agg_td);

    gmean_k<<<NB, 256, 0, stream>>>(agg_bu, agg_td, cnt, x2_bu, x2_td, gbuf);
    mlp_k<<<NB, 256, 0, stream>>>(gbuf, mw1, mb1, mw2, mb2, out);
}

// Round 6
// 561.449 us; speedup vs baseline: 20.9381x; 1.2160x over previous
//
#include <hip/hip_runtime.h>

#define NN 100000
#define NE 1600000
#define NB 500
#define NPG 200            // nodes per graph
#define BS 128             // nodes per bucket
#define NBUK 782           // ceil(NN / BS)
#define EPB 8192           // edges per block in hist
#define NEB 196            // ceil(NE / EPB)
#define EPB2 4096          // edges per block in stage2
#define NEB2 391           // ceil(NE / EPB2)
#define NBLK 1563          // ceil(NN / 64)

typedef unsigned short ushortT;
typedef __attribute__((ext_vector_type(8))) short bf16x8;
typedef __attribute__((ext_vector_type(4))) float f32x4;

#define MFMA16(a, b, c) __builtin_amdgcn_mfma_f32_16x16x32_bf16(a, b, c, 0, 0, 0)

__device__ inline ushortT f2bf(float f) {
    unsigned u = __float_as_uint(f);
    return (ushortT)((u + 0x7FFF + ((u >> 16) & 1)) >> 16);   // RNE
}
__device__ inline float bf2f(ushortT u) { return __uint_as_float((unsigned)u << 16); }
__device__ inline float4 bf4_to_f4(ushort4 u) {
    return make_float4(bf2f(u.x), bf2f(u.y), bf2f(u.z), bf2f(u.w));
}
__device__ inline bf16x8 cvt8(float4 f0, float4 f1) {
    bf16x8 r;
    r[0] = (short)f2bf(f0.x); r[1] = (short)f2bf(f0.y);
    r[2] = (short)f2bf(f0.z); r[3] = (short)f2bf(f0.w);
    r[4] = (short)f2bf(f1.x); r[5] = (short)f2bf(f1.y);
    r[6] = (short)f2bf(f1.z); r[7] = (short)f2bf(f1.w);
    return r;
}
// relu on 8 packed bf16 (sign-bit test is exact relu for bf16)
__device__ inline bf16x8 relu_bf8(uint4 w) {
    bf16x8 r;
    unsigned ws[4] = {w.x, w.y, w.z, w.w};
#pragma unroll
    for (int i = 0; i < 4; i++) {
        unsigned v = ws[i];
        unsigned lo = (v & 0x8000u) ? 0u : (v & 0xFFFFu);
        unsigned hi = (v & 0x80000000u) ? 0u : (v & 0xFFFF0000u);
        r[2 * i]     = (short)lo;
        r[2 * i + 1] = (short)(hi >> 16);
    }
    return r;
}

// ---------------- weight prep: WT[n][k] = bf16(W[k][n]), 4 matrices ----------------
__global__ void wprep_k(const float* __restrict__ w0, const float* __restrict__ w1,
                        const float* __restrict__ w2, const float* __restrict__ w3,
                        ushortT* __restrict__ wt) {
    int m = blockIdx.x >> 6;
    const float* w = (m == 0) ? w0 : (m == 1) ? w1 : (m == 2) ? w2 : w3;
    ushortT* o = wt + m * 16384;
    int idx = (blockIdx.x & 63) * 256 + threadIdx.x;   // n*128 + k
    int n = idx >> 7, k = idx & 127;
    o[idx] = f2bf(w[k * 128 + n]);
}

// ---------------- bucket histogram (both directions) ----------------
__global__ __launch_bounds__(512) void hist_k(const int* __restrict__ ei,
                                              int* __restrict__ bcnt_td,
                                              int* __restrict__ bcnt_bu) {
    __shared__ int h0[NBUK], h1[NBUK];
    const int t = threadIdx.x;
    for (int i = t; i < NBUK; i += 512) { h0[i] = 0; h1[i] = 0; }
    __syncthreads();
    int base = blockIdx.x * EPB;
#pragma unroll
    for (int j = 0; j < EPB / 512; j++) {
        int e = base + t + j * 512;
        if (e < NE) {
            int a = ei[e], b = ei[NE + e];
            atomicAdd(&h0[b >> 7], 1);
            atomicAdd(&h1[a >> 7], 1);
        }
    }
    __syncthreads();
    for (int i = t; i < NBUK; i += 512) {
        if (h0[i]) atomicAdd(&bcnt_td[i], h0[i]);
        if (h1[i]) atomicAdd(&bcnt_bu[i], h1[i]);
    }
}

// ---------------- bucket scan ----------------
__global__ __launch_bounds__(1024) void bscan_k(
    const int* __restrict__ c0, const int* __restrict__ c1,
    int* __restrict__ b0, int* __restrict__ b1,
    int* __restrict__ q0, int* __restrict__ q1) {
    const int* c = blockIdx.x ? c1 : c0;
    int* bb = blockIdx.x ? b1 : b0;
    int* bq = blockIdx.x ? q1 : q0;
    __shared__ int sh[1024];
    const int t = threadIdx.x;
    int v = (t < NBUK) ? c[t] : 0;
    sh[t] = v;
    __syncthreads();
#pragma unroll
    for (int off = 1; off < 1024; off <<= 1) {
        int add = (t >= off) ? sh[t - off] : 0;
        __syncthreads();
        sh[t] += add;
        __syncthreads();
    }
    int excl = sh[t] - v;
    if (t < NBUK) { bb[t] = excl; bq[t] = excl; }
    if (t == NBUK - 1) bb[NBUK] = sh[t];
}

// ---------------- stage both directions in ONE edge-list pass ----------------
__global__ __launch_bounds__(512) void stage2_k(const int* __restrict__ ei,
                                                int* __restrict__ bcur_td,
                                                int* __restrict__ bcur_bu,
                                                int* __restrict__ st_td,
                                                int* __restrict__ st_bu) {
    __shared__ int h0[NBUK], h1[NBUK];
    const int t = threadIdx.x;
    for (int i = t; i < NBUK; i += 512) { h0[i] = 0; h1[i] = 0; }
    __syncthreads();
    int base = blockIdx.x * EPB2;
    int a[EPB2 / 512], b[EPB2 / 512];
#pragma unroll
    for (int j = 0; j < EPB2 / 512; j++) {
        int e = base + t + j * 512;
        a[j] = -1;
        if (e < NE) {
            a[j] = ei[e]; b[j] = ei[NE + e];
            atomicAdd(&h0[b[j] >> 7], 1);
            atomicAdd(&h1[a[j] >> 7], 1);
        }
    }
    __syncthreads();
    for (int i = t; i < NBUK; i += 512) {
        int c0 = h0[i], c1 = h1[i];
        if (c0) h0[i] = atomicAdd(&bcur_td[i], c0);
        if (c1) h1[i] = atomicAdd(&bcur_bu[i], c1);
    }
    __syncthreads();
#pragma unroll
    for (int j = 0; j < EPB2 / 512; j++) {
        if (a[j] >= 0) {
            int o0 = atomicAdd(&h0[b[j] >> 7], 1);
            st_td[o0] = (a[j] << 7) | (b[j] & 127);
            int o1 = atomicAdd(&h1[a[j] >> 7], 1);
            st_bu[o1] = (b[j] << 7) | (a[j] & 127);
        }
    }
}

// ---------------- place both directions (grid = 2*NBUK) ----------------
__global__ __launch_bounds__(256) void place2_k(
    const int* __restrict__ st_td, const int* __restrict__ st_bu,
    const int* __restrict__ bb_td, const int* __restrict__ bb_bu,
    int* __restrict__ rp_td, int* __restrict__ rp_bu,
    int* __restrict__ csr_td, int* __restrict__ csr_bu,
    float* __restrict__ dinv_td, float* __restrict__ dinv_bu) {
    const int dir = blockIdx.x >= NBUK;
    const int bucket = dir ? blockIdx.x - NBUK : blockIdx.x;
    const int* stage = dir ? st_bu : st_td;
    const int* bbase = dir ? bb_bu : bb_td;
    int* rp = dir ? rp_bu : rp_td;
    int* csr = dir ? csr_bu : csr_td;
    float* dinv = dir ? dinv_bu : dinv_td;

    const int beg = bbase[bucket], end = bbase[bucket + 1];
    const int node0 = bucket << 7;
    __shared__ int lcnt[BS], lsc[BS], lcur[BS];
    const int t = threadIdx.x;
    if (t < BS) lcnt[t] = 0;
    __syncthreads();
    for (int i = beg + t; i < end; i += 256) atomicAdd(&lcnt[stage[i] & 127], 1);
    __syncthreads();
    if (t < BS) lsc[t] = lcnt[t];
    __syncthreads();
#pragma unroll
    for (int off = 1; off < BS; off <<= 1) {
        int add = (t < BS && t >= off) ? lsc[t - off] : 0;
        __syncthreads();
        if (t < BS) lsc[t] += add;
        __syncthreads();
    }
    if (t < BS) {
        int excl = lsc[t] - lcnt[t];
        lcur[t] = beg + excl;
        int node = node0 + t;
        if (node < NN) {
            rp[node] = beg + excl;
            dinv[node] = rsqrtf((float)(lcnt[t] + 1));
        }
    }
    if (bucket == NBUK - 1 && t == 0) rp[NN] = end;
    __syncthreads();
    for (int i = beg + t; i < end; i += 256) {
        int s = stage[i];
        int off = atomicAdd(&lcur[s & 127], 1);
        csr[off] = (int)((unsigned)s >> 7);
    }
}

// ---------------- counts per graph ----------------
__global__ void count_nodes_k(const int* __restrict__ batch, int* __restrict__ cnt) {
    int v = blockIdx.x * 256 + threadIdx.x;
    if (v >= NN) return;
    atomicAdd(&cnt[batch[v]], 1);
}

// ---------------- conv1 MFMA GEMM, both branches share A = concat(x,x_da) ----------------
__global__ __launch_bounds__(256) void gemm1x_k(
    const float* __restrict__ x, const float* __restrict__ xda,
    const ushortT* __restrict__ WTa, const ushortT* __restrict__ WTb,
    const float* __restrict__ dinv_a, const float* __restrict__ dinv_b,
    ushortT* __restrict__ hs_a, ushortT* __restrict__ hs_b) {
    const int t = threadIdx.x;
    const int wv = t >> 6, l = t & 63, lr = l & 15, lk = l >> 4;
    const int row0 = blockIdx.x * 64;
    const int cb0 = (wv * 2) * 16, cb1 = (wv * 2 + 1) * 16;

    bf16x8 bfr[2][2][4];   // [branch][ctile][kstep]
#pragma unroll
    for (int br = 0; br < 2; br++) {
        const ushortT* WT = br ? WTb : WTa;
#pragma unroll
        for (int c = 0; c < 2; c++) {
            const ushortT* base = WT + (size_t)((wv * 2 + c) * 16 + lr) * 128 + lk * 8;
#pragma unroll
            for (int kk = 0; kk < 4; kk++)
                bfr[br][c][kk] = *reinterpret_cast<const bf16x8*>(base + kk * 32);
        }
    }

#pragma unroll
    for (int rt = 0; rt < 4; rt++) {
        const int rtbase = row0 + rt * 16;
        int arow = rtbase + lr; if (arow >= NN) arow = NN - 1;
        bf16x8 af[4];
#pragma unroll
        for (int kk = 0; kk < 4; kk++) {
            int c8 = kk * 4 + lk;    // 8-col chunk 0..15 (12 from x, 4 from xda)
            float4 f0, f1;
            if (c8 < 12) {
                const float* p = x + (size_t)arow * 96 + c8 * 8;
                f0 = *(const float4*)p; f1 = *(const float4*)(p + 4);
            } else {
                const float* p = xda + (size_t)arow * 32 + (c8 - 12) * 8;
                f0 = *(const float4*)p; f1 = *(const float4*)(p + 4);
            }
            af[kk] = cvt8(f0, f1);
        }
        f32x4 a00 = {0,0,0,0}, a01 = {0,0,0,0}, a10 = {0,0,0,0}, a11 = {0,0,0,0};
#pragma unroll
        for (int kk = 0; kk < 4; kk++) {
            a00 = MFMA16(af[kk], bfr[0][0][kk], a00);
            a01 = MFMA16(af[kk], bfr[0][1][kk], a01);
            a10 = MFMA16(af[kk], bfr[1][0][kk], a10);
            a11 = MFMA16(af[kk], bfr[1][1][kk], a11);
        }
        const int srow = rtbase + lk * 4;
        float4 da = *(const float4*)(dinv_a + srow);
        float4 db = *(const float4*)(dinv_b + srow);
        const float* dap = (const float*)&da;
        const float* dbp = (const float*)&db;
#pragma unroll
        for (int e = 0; e < 4; e++) {
            int r = srow + e;
            if (r < NN) {
                size_t ro = (size_t)r * 128;
                hs_a[ro + cb0 + lr] = f2bf(a00[e] * dap[e]);
                hs_a[ro + cb1 + lr] = f2bf(a01[e] * dap[e]);
                hs_b[ro + cb0 + lr] = f2bf(a10[e] * dbp[e]);
                hs_b[ro + cb1 + lr] = f2bf(a11[e] * dbp[e]);
            }
        }
    }
}

// ---------------- conv2 MFMA GEMM, both branches via grid split ----------------
__global__ __launch_bounds__(256) void gemm2x_k(
    const ushortT* __restrict__ agg_a, const ushortT* __restrict__ agg_b,
    const ushortT* __restrict__ WTa, const ushortT* __restrict__ WTb,
    const float* __restrict__ rm_a, const float* __restrict__ rm_b,
    const float* __restrict__ dinv_a, const float* __restrict__ dinv_b,
    ushortT* __restrict__ hs_a, ushortT* __restrict__ hs_b) {
    const int brn = blockIdx.x >= NBLK;
    const ushortT* agg = brn ? agg_b : agg_a;
    const ushortT* WT  = brn ? WTb : WTa;
    const float* rm    = brn ? rm_b : rm_a;
    const float* dinv  = brn ? dinv_b : dinv_a;
    ushortT* hs        = brn ? hs_b : hs_a;
    const int blk = brn ? blockIdx.x - NBLK : blockIdx.x;
    const int t = threadIdx.x;
    const int wv = t >> 6, l = t & 63, lr = l & 15, lk = l >> 4;
    const int row0 = blk * 64;
    const int cb0 = (wv * 2) * 16, cb1 = (wv * 2 + 1) * 16;

    bf16x8 bfr[2][4];
#pragma unroll
    for (int c = 0; c < 2; c++) {
        const ushortT* base = WT + (size_t)((wv * 2 + c) * 16 + lr) * 128 + lk * 8;
#pragma unroll
        for (int kk = 0; kk < 4; kk++)
            bfr[c][kk] = *reinterpret_cast<const bf16x8*>(base + kk * 32);
    }

#pragma unroll
    for (int rt = 0; rt < 4; rt++) {
        const int rtbase = row0 + rt * 16;
        int arow = rtbase + lr; if (arow >= NN) arow = NN - 1;
        const ushortT* ap = agg + (size_t)arow * 128 + lk * 8;
        bf16x8 af[4];
#pragma unroll
        for (int kk = 0; kk < 4; kk++)
            af[kk] = relu_bf8(*reinterpret_cast<const uint4*>(ap + kk * 32));
        f32x4 a0 = {0,0,0,0}, a1 = {0,0,0,0};
#pragma unroll
        for (int kk = 0; kk < 4; kk++) {
            a0 = MFMA16(af[kk], bfr[0][kk], a0);
            a1 = MFMA16(af[kk], bfr[1][kk], a1);
        }
        const int srow = rtbase + lk * 4;
        float4 dv = *(const float4*)(dinv + srow);
        const float* dvp = (const float*)&dv;
#pragma unroll
        for (int e = 0; e < 4; e++) {
            int r = srow + e;
            if (r < NN) {
                int bg = r / NPG;
                size_t ro = (size_t)r * 128;
                float r0 = rm[(size_t)bg * 128 + cb0 + lr];
                float r1 = rm[(size_t)bg * 128 + cb1 + lr];
                hs[ro + cb0 + lr] = f2bf((a0[e] + r0) * dvp[e]);
                hs[ro + cb1 + lr] = f2bf((a1[e] + r1) * dvp[e]);
            }
        }
    }
}

// ---------------- fused dual-branch CSR gather ----------------
template <int MODE>   // 0: plain store (conv1 agg); 1: relu store (conv2 rows for mean)
__global__ __launch_bounds__(256) void gather2x_k(
    const int* __restrict__ rp_a, const int* __restrict__ csr_a,
    const float* __restrict__ dinv_a, const ushortT* __restrict__ hs_a,
    const float* __restrict__ bias_a,
    const int* __restrict__ rp_b, const int* __restrict__ csr_b,
    const float* __restrict__ dinv_b, const ushortT* __restrict__ hs_b,
    const float* __restrict__ bias_b,
    ushortT* __restrict__ out_a, ushortT* __restrict__ out_b) {
    int v = blockIdx.x * 8 + (threadIdx.x >> 5);
    if (v >= NN) return;
    const int lane = threadIdx.x & 31;
    int ba = rp_a[v], ea = rp_a[v + 1];
    int bb = rp_b[v], eb = rp_b[v + 1];
    float4 acc_a = bf4_to_f4(((const ushort4*)(hs_a + (size_t)v * 128))[lane]);  // self
    float4 acc_b = bf4_to_f4(((const ushort4*)(hs_b + (size_t)v * 128))[lane]);

    while (ba < ea || bb < eb) {
        int na = ea - ba; if (na > 32) na = 32; if (na < 0) na = 0;
        int nb = eb - bb; if (nb > 32) nb = 32; if (nb < 0) nb = 0;
        int ia = (lane < na) ? csr_a[ba + lane] : 0;
        int ib = (lane < nb) ? csr_b[bb + lane] : 0;
        for (int i = 0; i < 32; i += 8) {
            if (i >= na && i >= nb) break;
            ushort4 ua[8], ub[8];
            if (i < na) {
#pragma unroll
                for (int j = 0; j < 8; j++) {
                    int s = __shfl(ia, i + j, 32);
                    ua[j] = ((const ushort4*)(hs_a + (size_t)s * 128))[lane];
                }
            }
            if (i < nb) {
#pragma unroll
                for (int j = 0; j < 8; j++) {
                    int s = __shfl(ib, i + j, 32);
                    ub[j] = ((const ushort4*)(hs_b + (size_t)s * 128))[lane];
                }
            }
            if (i < na) {
#pragma unroll
                for (int j = 0; j < 8; j++)
                    if (i + j < na) {
                        float4 f = bf4_to_f4(ua[j]);
                        acc_a.x += f.x; acc_a.y += f.y; acc_a.z += f.z; acc_a.w += f.w;
                    }
            }
            if (i < nb) {
#pragma unroll
                for (int j = 0; j < 8; j++)
                    if (i + j < nb) {
                        float4 f = bf4_to_f4(ub[j]);
                        acc_b.x += f.x; acc_b.y += f.y; acc_b.z += f.z; acc_b.w += f.w;
                    }
            }
        }
        ba += 32; bb += 32;
    }

    float da = dinv_a[v], db = dinv_b[v];
    float4 pa = ((const float4*)bias_a)[lane];
    float4 pb = ((const float4*)bias_b)[lane];
    float4 oa = make_float4(fmaf(acc_a.x, da, pa.x), fmaf(acc_a.y, da, pa.y),
                            fmaf(acc_a.z, da, pa.z), fmaf(acc_a.w, da, pa.w));
    float4 ob = make_float4(fmaf(acc_b.x, db, pb.x), fmaf(acc_b.y, db, pb.y),
                            fmaf(acc_b.z, db, pb.z), fmaf(acc_b.w, db, pb.w));
    if (MODE == 1) {
        oa.x = fmaxf(oa.x, 0.f); oa.y = fmaxf(oa.y, 0.f); oa.z = fmaxf(oa.z, 0.f); oa.w = fmaxf(oa.w, 0.f);
        ob.x = fmaxf(ob.x, 0.f); ob.y = fmaxf(ob.y, 0.f); ob.z = fmaxf(ob.z, 0.f); ob.w = fmaxf(ob.w, 0.f);
    }
    ((ushort4*)(out_a + (size_t)v * 128))[lane] =
        make_ushort4(f2bf(oa.x), f2bf(oa.y), f2bf(oa.z), f2bf(oa.w));
    ((ushort4*)(out_b + (size_t)v * 128))[lane] =
        make_ushort4(f2bf(ob.x), f2bf(ob.y), f2bf(ob.z), f2bf(ob.w));
}

// ---------------- roots: x2root + rootmix, both branches ----------------
__global__ void roots_k(
    const float* __restrict__ x, const float* __restrict__ xda,
    const int* __restrict__ root,
    const ushortT* __restrict__ agg_a, const ushortT* __restrict__ agg_b,
    const float* __restrict__ W2a, const float* __restrict__ W2b,
    float* __restrict__ x2a, float* __restrict__ x2b,
    float* __restrict__ rma, float* __restrict__ rmb) {
    __shared__ float xr[128];
    int b = blockIdx.x, t = threadIdx.x;
    int r = root[b];
    if (t < 128) {
        float val = (t < 96) ? x[(size_t)r * 96 + t] : xda[(size_t)r * 32 + (t - 96)];
        xr[t] = fmaxf(val, 0.f);
    }
    __syncthreads();
    int br = t >> 7, c = t & 127;
    const ushortT* agg = br ? agg_b : agg_a;
    const float* W2 = br ? W2b : W2a;
    float* x2 = br ? x2b : x2a;
    float* rm = br ? rmb : rma;
    x2[(size_t)b * 128 + c] = bf2f(agg[(size_t)r * 128 + c]);
    float acc = 0.f;
#pragma unroll 8
    for (int k = 0; k < 128; k++)
        acc = fmaf(xr[k], W2[(size_t)(128 + k) * 128 + c], acc);
    rm[(size_t)b * 128 + c] = acc;
}

// ---------------- graph mean (contiguous segments) ----------------
__global__ void gmean_k(const ushortT* __restrict__ ra, const ushortT* __restrict__ rb,
                        const int* __restrict__ cnt,
                        const float* __restrict__ x2a, const float* __restrict__ x2b,
                        float* __restrict__ gbuf) {
    int b = blockIdx.x, t = threadIdx.x;
    int br = t >> 7, c = t & 127;
    const ushortT* src = br ? rb : ra;
    size_t base = (size_t)b * NPG * 128 + c;
    float s = 0.f;
#pragma unroll 4
    for (int r = 0; r < NPG; r++)
        s += bf2f(src[base + (size_t)r * 128]);
    float inv = 1.0f / (float)cnt[b];
    const float* x2 = br ? x2b : x2a;
    int o = br ? 256 : 0;
    gbuf[(size_t)b * 512 + o + c] = s * inv;
    gbuf[(size_t)b * 512 + o + 128 + c] = x2[(size_t)b * 128 + c];
}

// ---------------- final MLP ----------------
__global__ void mlp_k(const float* __restrict__ g, const float* __restrict__ w1,
                      const float* __restrict__ b1, const float* __restrict__ w2,
                      const float* __restrict__ b2, float* __restrict__ out) {
    __shared__ float gs[512];
    __shared__ float parts[4][2];
    int b = blockIdx.x, t = threadIdx.x;
    gs[t] = g[(size_t)b * 512 + t];
    gs[t + 256] = g[(size_t)b * 512 + 256 + t];
    __syncthreads();
    float acc = b1[t];
#pragma unroll 8
    for (int k = 0; k < 512; k++)
        acc = fmaf(gs[k], w1[(size_t)k * 256 + t], acc);
    float hv = fmaxf(acc, 0.f);
    float p0 = hv * w2[t * 2 + 0];
    float p1 = hv * w2[t * 2 + 1];
#pragma unroll
    for (int off = 32; off; off >>= 1) {
        p0 += __shfl_down(p0, off);
        p1 += __shfl_down(p1, off);
    }
    int w = t >> 6;
    if ((t & 63) == 0) { parts[w][0] = p0; parts[w][1] = p1; }
    __syncthreads();
    if (t == 0) {
        out[b * 2 + 0] = parts[0][0] + parts[1][0] + parts[2][0] + parts[3][0] + b2[0];
        out[b * 2 + 1] = parts[0][1] + parts[1][1] + parts[2][1] + parts[3][1] + b2[1];
    }
}

// ---------------- launch ----------------
extern "C" void kernel_launch(void* const* d_in, const int* in_sizes, int n_in,
                              void* d_out, int out_size, void* d_ws, size_t ws_size,
                              hipStream_t stream) {
    const float* x     = (const float*)d_in[0];
    const float* xda   = (const float*)d_in[1];
    const int*   ei    = (const int*)d_in[2];
    const int*   batch = (const int*)d_in[3];
    const int*   root  = (const int*)d_in[4];
    const float* td_w1 = (const float*)d_in[5];
    const float* td_b1 = (const float*)d_in[6];
    const float* td_w2 = (const float*)d_in[7];
    const float* td_b2 = (const float*)d_in[8];
    const float* bu_w1 = (const float*)d_in[9];
    const float* bu_b1 = (const float*)d_in[10];
    const float* bu_w2 = (const float*)d_in[11];
    const float* bu_b2 = (const float*)d_in[12];
    const float* mw1   = (const float*)d_in[13];
    const float* mb1   = (const float*)d_in[14];
    const float* mw2   = (const float*)d_in[15];
    const float* mb2   = (const float*)d_in[16];
    float* out = (float*)d_out;

    // workspace layout
    ushortT* agg_bu  = (ushortT*)d_ws;                       // NN*128 bf16
    ushortT* agg_td  = agg_bu + (size_t)NN * 128;
    ushortT* hs_bu   = agg_td + (size_t)NN * 128;
    ushortT* hs_td   = hs_bu + (size_t)NN * 128;
    float*   dinv_td = (float*)(hs_td + (size_t)NN * 128);   // NN
    float*   dinv_bu = dinv_td + NN;                         // NN
    float*   x2_bu   = dinv_bu + NN;                         // NB*128
    float*   x2_td   = x2_bu + (size_t)NB * 128;
    float*   rm_bu   = x2_td + (size_t)NB * 128;             // NB*128
    float*   rm_td   = rm_bu + (size_t)NB * 128;
    float*   gbuf    = rm_td + (size_t)NB * 128;             // NB*512
    ushortT* wt1_bu  = (ushortT*)(gbuf + (size_t)NB * 512);  // 16384 each
    ushortT* wt1_td  = wt1_bu + 16384;
    ushortT* wt2_bu  = wt1_td + 16384;
    ushortT* wt2_td  = wt2_bu + 16384;
    int*     cnt     = (int*)(wt2_td + 16384);               // NB
    int*     bcnt_td = cnt + NB;                             // NBUK
    int*     bcnt_bu = bcnt_td + NBUK;                       // NBUK
    int*     bbase_td= bcnt_bu + NBUK;                       // NBUK+1
    int*     bbase_bu= bbase_td + NBUK + 1;                  // NBUK+1
    int*     bcur_td = bbase_bu + NBUK + 1;                  // NBUK
    int*     bcur_bu = bcur_td + NBUK;                       // NBUK
    int*     rp_td   = bcur_bu + NBUK;                       // NN+1
    int*     rp_bu   = rp_td + NN + 1;                       // NN+1
    int*     csr_td  = rp_bu + NN + 1;                       // NE
    int*     csr_bu  = csr_td + NE;                          // NE
    int*     st_td   = (int*)agg_bu;                         // NE ints (agg dead in preproc)
    int*     st_bu   = st_td + NE;                           // NE ints

    hipMemsetAsync(cnt, 0, (size_t)(NB + 2 * NBUK) * sizeof(int), stream);

    wprep_k<<<4 * 64, 256, 0, stream>>>(bu_w1, td_w1, bu_w2, td_w2, wt1_bu);
    hist_k<<<NEB, 512, 0, stream>>>(ei, bcnt_td, bcnt_bu);
    count_nodes_k<<<(NN + 255) / 256, 256, 0, stream>>>(batch, cnt);
    bscan_k<<<2, 1024, 0, stream>>>(bcnt_td, bcnt_bu, bbase_td, bbase_bu, bcur_td, bcur_bu);
    stage2_k<<<NEB2, 512, 0, stream>>>(ei, bcur_td, bcur_bu, st_td, st_bu);
    place2_k<<<2 * NBUK, 256, 0, stream>>>(st_td, st_bu, bbase_td, bbase_bu,
                                           rp_td, rp_bu, csr_td, csr_bu, dinv_td, dinv_bu);

    // conv1 (both branches fused, MFMA)
    gemm1x_k<<<NBLK, 256, 0, stream>>>(x, xda, wt1_bu, wt1_td, dinv_bu, dinv_td, hs_bu, hs_td);
    gather2x_k<0><<<(NN + 7) / 8, 256, 0, stream>>>(
        rp_bu, csr_bu, dinv_bu, hs_bu, bu_b1,
        rp_td, csr_td, dinv_td, hs_td, td_b1, agg_bu, agg_td);

    roots_k<<<NB, 256, 0, stream>>>(x, xda, root, agg_bu, agg_td, bu_w2, td_w2,
                                    x2_bu, x2_td, rm_bu, rm_td);

    // conv2 (both branches in one grid, MFMA)
    gemm2x_k<<<2 * NBLK, 256, 0, stream>>>(agg_bu, agg_td, wt2_bu, wt2_td,
                                           rm_bu, rm_td, dinv_bu, dinv_td, hs_bu, hs_td);
    gather2x_k<1><<<(NN + 7) / 8, 256, 0, stream>>>(
        rp_bu, csr_bu, dinv_bu, hs_bu, bu_b2,
        rp_td, csr_td, dinv_td, hs_td, td_b2, agg_bu, agg_td);

    gmean_k<<<NB, 256, 0, stream>>>(agg_bu, agg_td, cnt, x2_bu, x2_td, gbuf);
    mlp_k<<<NB, 256, 0, stream>>>(gbuf, mw1, mb1, mw2, mb2, out);
}

// Round 7
// 475.571 us; speedup vs baseline: 24.7191x; 1.1806x over previous
//
#include <hip/hip_runtime.h>

#define NN 100000
#define NE 1600000
#define NB 500
#define NPG 200            // nodes per graph (batch = arange // 200 exactly)
#define BS 128             // nodes per bucket
#define NBUK 782           // ceil(NN / BS)
#define SLAB 2560          // slab capacity per bucket (lambda=2048, 11 sigma)
#define EPB2 4096          // edges per block in stage
#define NEB2 391           // ceil(NE / EPB2)
#define NBLK 1563          // ceil(NN / 64)

typedef unsigned short ushortT;
typedef __attribute__((ext_vector_type(8))) short bf16x8;
typedef __attribute__((ext_vector_type(4))) float f32x4;

#define MFMA16(a, b, c) __builtin_amdgcn_mfma_f32_16x16x32_bf16(a, b, c, 0, 0, 0)

__device__ inline ushortT f2bf(float f) {
    unsigned u = __float_as_uint(f);
    return (ushortT)((u + 0x7FFF + ((u >> 16) & 1)) >> 16);   // RNE
}
__device__ inline float bf2f(ushortT u) { return __uint_as_float((unsigned)u << 16); }
// accumulate 2 packed bf16 into 2 f32
__device__ inline void addbf2(float& a0, float& a1, unsigned w) {
    a0 += __uint_as_float(w << 16);
    a1 += __uint_as_float(w & 0xFFFF0000u);
}
__device__ inline void addbf8(float* acc, uint4 w) {
    addbf2(acc[0], acc[1], w.x);
    addbf2(acc[2], acc[3], w.y);
    addbf2(acc[4], acc[5], w.z);
    addbf2(acc[6], acc[7], w.w);
}
__device__ inline bf16x8 cvt8(float4 f0, float4 f1) {
    bf16x8 r;
    r[0] = (short)f2bf(f0.x); r[1] = (short)f2bf(f0.y);
    r[2] = (short)f2bf(f0.z); r[3] = (short)f2bf(f0.w);
    r[4] = (short)f2bf(f1.x); r[5] = (short)f2bf(f1.y);
    r[6] = (short)f2bf(f1.z); r[7] = (short)f2bf(f1.w);
    return r;
}
__device__ inline bf16x8 relu_bf8(uint4 w) {
    bf16x8 r;
    unsigned ws[4] = {w.x, w.y, w.z, w.w};
#pragma unroll
    for (int i = 0; i < 4; i++) {
        unsigned v = ws[i];
        unsigned lo = (v & 0x8000u) ? 0u : (v & 0xFFFFu);
        unsigned hi = (v & 0x80000000u) ? 0u : (v & 0xFFFF0000u);
        r[2 * i]     = (short)lo;
        r[2 * i + 1] = (short)(hi >> 16);
    }
    return r;
}

// ---------------- weight prep: WT[n][k] = bf16(W[k][n]), 4 matrices ----------------
__global__ void wprep_k(const float* __restrict__ w0, const float* __restrict__ w1,
                        const float* __restrict__ w2, const float* __restrict__ w3,
                        ushortT* __restrict__ wt) {
    int m = blockIdx.x >> 6;
    const float* w = (m == 0) ? w0 : (m == 1) ? w1 : (m == 2) ? w2 : w3;
    ushortT* o = wt + m * 16384;
    int idx = (blockIdx.x & 63) * 256 + threadIdx.x;   // n*128 + k
    int n = idx >> 7, k = idx & 127;
    o[idx] = f2bf(w[k * 128 + n]);
}

// ---------------- slab staging: single pass, no prior histogram ----------------
// bcnt_* must be zeroed; ends holding per-bucket counts.
__global__ __launch_bounds__(512) void stage_slab_k(const int* __restrict__ ei,
                                                    int* __restrict__ bcnt_td,
                                                    int* __restrict__ bcnt_bu,
                                                    int* __restrict__ st_td,
                                                    int* __restrict__ st_bu) {
    __shared__ int h0[NBUK], h1[NBUK];
    const int t = threadIdx.x;
    for (int i = t; i < NBUK; i += 512) { h0[i] = 0; h1[i] = 0; }
    __syncthreads();
    int base = blockIdx.x * EPB2;
    int a[EPB2 / 512], b[EPB2 / 512];
#pragma unroll
    for (int j = 0; j < EPB2 / 512; j++) {
        int e = base + t + j * 512;
        a[j] = -1;
        if (e < NE) {
            a[j] = ei[e]; b[j] = ei[NE + e];
            atomicAdd(&h0[b[j] >> 7], 1);
            atomicAdd(&h1[a[j] >> 7], 1);
        }
    }
    __syncthreads();
    for (int i = t; i < NBUK; i += 512) {
        int c0 = h0[i], c1 = h1[i];
        if (c0) h0[i] = atomicAdd(&bcnt_td[i], c0);   // slab-local base
        if (c1) h1[i] = atomicAdd(&bcnt_bu[i], c1);
    }
    __syncthreads();
#pragma unroll
    for (int j = 0; j < EPB2 / 512; j++) {
        if (a[j] >= 0) {
            int bk0 = b[j] >> 7;
            int o0 = atomicAdd(&h0[bk0], 1);
            st_td[bk0 * SLAB + o0] = (a[j] << 7) | (b[j] & 127);
            int bk1 = a[j] >> 7;
            int o1 = atomicAdd(&h1[bk1], 1);
            st_bu[bk1 * SLAB + o1] = (b[j] << 7) | (a[j] & 127);
        }
    }
}

// ---------------- bucket scan: bcnt -> bbase (exclusive) ----------------
__global__ __launch_bounds__(1024) void bscan_k(
    const int* __restrict__ c0, const int* __restrict__ c1,
    int* __restrict__ b0, int* __restrict__ b1) {
    const int* c = blockIdx.x ? c1 : c0;
    int* bb = blockIdx.x ? b1 : b0;
    __shared__ int sh[1024];
    const int t = threadIdx.x;
    int v = (t < NBUK) ? c[t] : 0;
    sh[t] = v;
    __syncthreads();
#pragma unroll
    for (int off = 1; off < 1024; off <<= 1) {
        int add = (t >= off) ? sh[t - off] : 0;
        __syncthreads();
        sh[t] += add;
        __syncthreads();
    }
    int excl = sh[t] - v;
    if (t < NBUK) bb[t] = excl;
    if (t == NBUK - 1) bb[NBUK] = sh[t];
}

// ---------------- place from slabs (grid = 2*NBUK) -> rowptr, csr, dinv ----------------
__global__ __launch_bounds__(256) void place2_k(
    const int* __restrict__ st_td, const int* __restrict__ st_bu,
    const int* __restrict__ bcnt_td, const int* __restrict__ bcnt_bu,
    const int* __restrict__ bb_td, const int* __restrict__ bb_bu,
    int* __restrict__ rp_td, int* __restrict__ rp_bu,
    int* __restrict__ csr_td, int* __restrict__ csr_bu,
    float* __restrict__ dinv_td, float* __restrict__ dinv_bu) {
    const int dir = blockIdx.x >= NBUK;
    const int bucket = dir ? blockIdx.x - NBUK : blockIdx.x;
    const int* stage = (dir ? st_bu : st_td) + bucket * SLAB;
    const int n = (dir ? bcnt_bu : bcnt_td)[bucket];
    const int obase = (dir ? bb_bu : bb_td)[bucket];
    int* rp = dir ? rp_bu : rp_td;
    int* csr = dir ? csr_bu : csr_td;
    float* dinv = dir ? dinv_bu : dinv_td;

    const int node0 = bucket << 7;
    __shared__ int lcnt[BS], lsc[BS], lcur[BS];
    const int t = threadIdx.x;
    if (t < BS) lcnt[t] = 0;
    __syncthreads();
    for (int i = t; i < n; i += 256) atomicAdd(&lcnt[stage[i] & 127], 1);
    __syncthreads();
    if (t < BS) lsc[t] = lcnt[t];
    __syncthreads();
#pragma unroll
    for (int off = 1; off < BS; off <<= 1) {
        int add = (t < BS && t >= off) ? lsc[t - off] : 0;
        __syncthreads();
        if (t < BS) lsc[t] += add;
        __syncthreads();
    }
    if (t < BS) {
        int excl = lsc[t] - lcnt[t];
        lcur[t] = obase + excl;
        int node = node0 + t;
        if (node < NN) {
            rp[node] = obase + excl;
            dinv[node] = rsqrtf((float)(lcnt[t] + 1));
        }
    }
    if (bucket == NBUK - 1 && t == 0) rp[NN] = obase + n;
    __syncthreads();
    for (int i = t; i < n; i += 256) {
        int s = stage[i];
        int off = atomicAdd(&lcur[s & 127], 1);
        csr[off] = (int)((unsigned)s >> 7);
    }
}

// ---------------- conv1 MFMA GEMM, both branches share A = concat(x,x_da) ----------------
__global__ __launch_bounds__(256) void gemm1x_k(
    const float* __restrict__ x, const float* __restrict__ xda,
    const ushortT* __restrict__ WTa, const ushortT* __restrict__ WTb,
    const float* __restrict__ dinv_a, const float* __restrict__ dinv_b,
    ushortT* __restrict__ hs_a, ushortT* __restrict__ hs_b) {
    const int t = threadIdx.x;
    const int wv = t >> 6, l = t & 63, lr = l & 15, lk = l >> 4;
    const int row0 = blockIdx.x * 64;
    const int cb0 = (wv * 2) * 16, cb1 = (wv * 2 + 1) * 16;

    bf16x8 bfr[2][2][4];
#pragma unroll
    for (int br = 0; br < 2; br++) {
        const ushortT* WT = br ? WTb : WTa;
#pragma unroll
        for (int c = 0; c < 2; c++) {
            const ushortT* base = WT + (size_t)((wv * 2 + c) * 16 + lr) * 128 + lk * 8;
#pragma unroll
            for (int kk = 0; kk < 4; kk++)
                bfr[br][c][kk] = *reinterpret_cast<const bf16x8*>(base + kk * 32);
        }
    }

#pragma unroll
    for (int rt = 0; rt < 4; rt++) {
        const int rtbase = row0 + rt * 16;
        int arow = rtbase + lr; if (arow >= NN) arow = NN - 1;
        bf16x8 af[4];
#pragma unroll
        for (int kk = 0; kk < 4; kk++) {
            int c8 = kk * 4 + lk;
            float4 f0, f1;
            if (c8 < 12) {
                const float* p = x + (size_t)arow * 96 + c8 * 8;
                f0 = *(const float4*)p; f1 = *(const float4*)(p + 4);
            } else {
                const float* p = xda + (size_t)arow * 32 + (c8 - 12) * 8;
                f0 = *(const float4*)p; f1 = *(const float4*)(p + 4);
            }
            af[kk] = cvt8(f0, f1);
        }
        f32x4 a00 = {0,0,0,0}, a01 = {0,0,0,0}, a10 = {0,0,0,0}, a11 = {0,0,0,0};
#pragma unroll
        for (int kk = 0; kk < 4; kk++) {
            a00 = MFMA16(af[kk], bfr[0][0][kk], a00);
            a01 = MFMA16(af[kk], bfr[0][1][kk], a01);
            a10 = MFMA16(af[kk], bfr[1][0][kk], a10);
            a11 = MFMA16(af[kk], bfr[1][1][kk], a11);
        }
        const int srow = rtbase + lk * 4;
        float4 da = *(const float4*)(dinv_a + srow);
        float4 db = *(const float4*)(dinv_b + srow);
        const float* dap = (const float*)&da;
        const float* dbp = (const float*)&db;
#pragma unroll
        for (int e = 0; e < 4; e++) {
            int r = srow + e;
            if (r < NN) {
                size_t ro = (size_t)r * 128;
                hs_a[ro + cb0 + lr] = f2bf(a00[e] * dap[e]);
                hs_a[ro + cb1 + lr] = f2bf(a01[e] * dap[e]);
                hs_b[ro + cb0 + lr] = f2bf(a10[e] * dbp[e]);
                hs_b[ro + cb1 + lr] = f2bf(a11[e] * dbp[e]);
            }
        }
    }
}

// ---------------- conv2 MFMA GEMM, both branches via grid split ----------------
__global__ __launch_bounds__(256) void gemm2x_k(
    const ushortT* __restrict__ agg_a, const ushortT* __restrict__ agg_b,
    const ushortT* __restrict__ WTa, const ushortT* __restrict__ WTb,
    const float* __restrict__ rm_a, const float* __restrict__ rm_b,
    const float* __restrict__ dinv_a, const float* __restrict__ dinv_b,
    ushortT* __restrict__ hs_a, ushortT* __restrict__ hs_b) {
    const int brn = blockIdx.x >= NBLK;
    const ushortT* agg = brn ? agg_b : agg_a;
    const ushortT* WT  = brn ? WTb : WTa;
    const float* rm    = brn ? rm_b : rm_a;
    const float* dinv  = brn ? dinv_b : dinv_a;
    ushortT* hs        = brn ? hs_b : hs_a;
    const int blk = brn ? blockIdx.x - NBLK : blockIdx.x;
    const int t = threadIdx.x;
    const int wv = t >> 6, l = t & 63, lr = l & 15, lk = l >> 4;
    const int row0 = blk * 64;
    const int cb0 = (wv * 2) * 16, cb1 = (wv * 2 + 1) * 16;

    bf16x8 bfr[2][4];
#pragma unroll
    for (int c = 0; c < 2; c++) {
        const ushortT* base = WT + (size_t)((wv * 2 + c) * 16 + lr) * 128 + lk * 8;
#pragma unroll
        for (int kk = 0; kk < 4; kk++)
            bfr[c][kk] = *reinterpret_cast<const bf16x8*>(base + kk * 32);
    }

#pragma unroll
    for (int rt = 0; rt < 4; rt++) {
        const int rtbase = row0 + rt * 16;
        int arow = rtbase + lr; if (arow >= NN) arow = NN - 1;
        const ushortT* ap = agg + (size_t)arow * 128 + lk * 8;
        bf16x8 af[4];
#pragma unroll
        for (int kk = 0; kk < 4; kk++)
            af[kk] = relu_bf8(*reinterpret_cast<const uint4*>(ap + kk * 32));
        f32x4 a0 = {0,0,0,0}, a1 = {0,0,0,0};
#pragma unroll
        for (int kk = 0; kk < 4; kk++) {
            a0 = MFMA16(af[kk], bfr[0][kk], a0);
            a1 = MFMA16(af[kk], bfr[1][kk], a1);
        }
        const int srow = rtbase + lk * 4;
        float4 dv = *(const float4*)(dinv + srow);
        const float* dvp = (const float*)&dv;
#pragma unroll
        for (int e = 0; e < 4; e++) {
            int r = srow + e;
            if (r < NN) {
                int bg = r / NPG;
                size_t ro = (size_t)r * 128;
                float r0 = rm[(size_t)bg * 128 + cb0 + lr];
                float r1 = rm[(size_t)bg * 128 + cb1 + lr];
                hs[ro + cb0 + lr] = f2bf((a0[e] + r0) * dvp[e]);
                hs[ro + cb1 + lr] = f2bf((a1[e] + r1) * dvp[e]);
            }
        }
    }
}

// ---------------- fused dual-branch CSR gather: 16 lanes/node, 16B/lane ----------------
template <int MODE>   // 0: plain store (conv1 agg); 1: relu store (conv2 rows for mean)
__global__ __launch_bounds__(256) void gather16_k(
    const int* __restrict__ rp_a, const int* __restrict__ csr_a,
    const float* __restrict__ dinv_a, const ushortT* __restrict__ hs_a,
    const float* __restrict__ bias_a,
    const int* __restrict__ rp_b, const int* __restrict__ csr_b,
    const float* __restrict__ dinv_b, const ushortT* __restrict__ hs_b,
    const float* __restrict__ bias_b,
    ushortT* __restrict__ out_a, ushortT* __restrict__ out_b) {
    int v = blockIdx.x * 16 + (threadIdx.x >> 4);
    if (v >= NN) return;
    const int lane = threadIdx.x & 15;   // 8 cols per lane: [lane*8, lane*8+8)
    int ba = rp_a[v], ea = rp_a[v + 1];
    int bb = rp_b[v], eb = rp_b[v + 1];
    float acc_a[8], acc_b[8];
#pragma unroll
    for (int k = 0; k < 8; k++) { acc_a[k] = 0.f; acc_b[k] = 0.f; }
    addbf8(acc_a, *(const uint4*)(hs_a + (size_t)v * 128 + lane * 8));   // self
    addbf8(acc_b, *(const uint4*)(hs_b + (size_t)v * 128 + lane * 8));

    while (ba < ea || bb < eb) {
        int na = ea - ba; if (na > 16) na = 16; if (na < 0) na = 0;
        int nb = eb - bb; if (nb > 16) nb = 16; if (nb < 0) nb = 0;
        int ia = (lane < na) ? csr_a[ba + lane] : 0;
        int ib = (lane < nb) ? csr_b[bb + lane] : 0;
#pragma unroll
        for (int i = 0; i < 16; i += 8) {
            if (i >= na && i >= nb) break;
            uint4 ua[8], ub[8];
            if (i < na) {
#pragma unroll
                for (int j = 0; j < 8; j++) {
                    int s = __shfl(ia, i + j, 16);
                    ua[j] = *(const uint4*)(hs_a + (size_t)s * 128 + lane * 8);
                }
            }
            if (i < nb) {
#pragma unroll
                for (int j = 0; j < 8; j++) {
                    int s = __shfl(ib, i + j, 16);
                    ub[j] = *(const uint4*)(hs_b + (size_t)s * 128 + lane * 8);
                }
            }
            if (i < na) {
#pragma unroll
                for (int j = 0; j < 8; j++)
                    if (i + j < na) addbf8(acc_a, ua[j]);
            }
            if (i < nb) {
#pragma unroll
                for (int j = 0; j < 8; j++)
                    if (i + j < nb) addbf8(acc_b, ub[j]);
            }
        }
        ba += 16; bb += 16;
    }

    float da = dinv_a[v], db = dinv_b[v];
    float4 pa0 = *(const float4*)(bias_a + lane * 8);
    float4 pa1 = *(const float4*)(bias_a + lane * 8 + 4);
    float4 pb0 = *(const float4*)(bias_b + lane * 8);
    float4 pb1 = *(const float4*)(bias_b + lane * 8 + 4);
    float oa[8], ob[8];
    const float* pap = (const float*)&pa0;   // pa0,pa1 contiguous? not guaranteed; do explicit
    oa[0] = fmaf(acc_a[0], da, pa0.x); oa[1] = fmaf(acc_a[1], da, pa0.y);
    oa[2] = fmaf(acc_a[2], da, pa0.z); oa[3] = fmaf(acc_a[3], da, pa0.w);
    oa[4] = fmaf(acc_a[4], da, pa1.x); oa[5] = fmaf(acc_a[5], da, pa1.y);
    oa[6] = fmaf(acc_a[6], da, pa1.z); oa[7] = fmaf(acc_a[7], da, pa1.w);
    ob[0] = fmaf(acc_b[0], db, pb0.x); ob[1] = fmaf(acc_b[1], db, pb0.y);
    ob[2] = fmaf(acc_b[2], db, pb0.z); ob[3] = fmaf(acc_b[3], db, pb0.w);
    ob[4] = fmaf(acc_b[4], db, pb1.x); ob[5] = fmaf(acc_b[5], db, pb1.y);
    ob[6] = fmaf(acc_b[6], db, pb1.z); ob[7] = fmaf(acc_b[7], db, pb1.w);
    (void)pap;
    if (MODE == 1) {
#pragma unroll
        for (int k = 0; k < 8; k++) { oa[k] = fmaxf(oa[k], 0.f); ob[k] = fmaxf(ob[k], 0.f); }
    }
    uint4 wa, wb;
    wa.x = (unsigned)f2bf(oa[0]) | ((unsigned)f2bf(oa[1]) << 16);
    wa.y = (unsigned)f2bf(oa[2]) | ((unsigned)f2bf(oa[3]) << 16);
    wa.z = (unsigned)f2bf(oa[4]) | ((unsigned)f2bf(oa[5]) << 16);
    wa.w = (unsigned)f2bf(oa[6]) | ((unsigned)f2bf(oa[7]) << 16);
    wb.x = (unsigned)f2bf(ob[0]) | ((unsigned)f2bf(ob[1]) << 16);
    wb.y = (unsigned)f2bf(ob[2]) | ((unsigned)f2bf(ob[3]) << 16);
    wb.z = (unsigned)f2bf(ob[4]) | ((unsigned)f2bf(ob[5]) << 16);
    wb.w = (unsigned)f2bf(ob[6]) | ((unsigned)f2bf(ob[7]) << 16);
    *(uint4*)(out_a + (size_t)v * 128 + lane * 8) = wa;
    *(uint4*)(out_b + (size_t)v * 128 + lane * 8) = wb;
}

// ---------------- roots: x2root + rootmix, both branches ----------------
__global__ void roots_k(
    const float* __restrict__ x, const float* __restrict__ xda,
    const int* __restrict__ root,
    const ushortT* __restrict__ agg_a, const ushortT* __restrict__ agg_b,
    const float* __restrict__ W2a, const float* __restrict__ W2b,
    float* __restrict__ x2a, float* __restrict__ x2b,
    float* __restrict__ rma, float* __restrict__ rmb) {
    __shared__ float xr[128];
    int b = blockIdx.x, t = threadIdx.x;
    int r = root[b];
    if (t < 128) {
        float val = (t < 96) ? x[(size_t)r * 96 + t] : xda[(size_t)r * 32 + (t - 96)];
        xr[t] = fmaxf(val, 0.f);
    }
    __syncthreads();
    int br = t >> 7, c = t & 127;
    const ushortT* agg = br ? agg_b : agg_a;
    const float* W2 = br ? W2b : W2a;
    float* x2 = br ? x2b : x2a;
    float* rm = br ? rmb : rma;
    x2[(size_t)b * 128 + c] = bf2f(agg[(size_t)r * 128 + c]);
    float acc = 0.f;
#pragma unroll 8
    for (int k = 0; k < 128; k++)
        acc = fmaf(xr[k], W2[(size_t)(128 + k) * 128 + c], acc);
    rm[(size_t)b * 128 + c] = acc;
}

// ---------------- graph mean (contiguous segments, cnt == NPG) ----------------
__global__ void gmean_k(const ushortT* __restrict__ ra, const ushortT* __restrict__ rb,
                        const float* __restrict__ x2a, const float* __restrict__ x2b,
                        float* __restrict__ gbuf) {
    int b = blockIdx.x, t = threadIdx.x;
    int br = t >> 7, c = t & 127;
    const ushortT* src = br ? rb : ra;
    size_t base = (size_t)b * NPG * 128 + c;
    float s = 0.f;
#pragma unroll 4
    for (int r = 0; r < NPG; r++)
        s += bf2f(src[base + (size_t)r * 128]);
    const float* x2 = br ? x2b : x2a;
    int o = br ? 256 : 0;
    gbuf[(size_t)b * 512 + o + c] = s * (1.0f / NPG);
    gbuf[(size_t)b * 512 + o + 128 + c] = x2[(size_t)b * 128 + c];
}

// ---------------- final MLP ----------------
__global__ void mlp_k(const float* __restrict__ g, const float* __restrict__ w1,
                      const float* __restrict__ b1, const float* __restrict__ w2,
                      const float* __restrict__ b2, float* __restrict__ out) {
    __shared__ float gs[512];
    __shared__ float parts[4][2];
    int b = blockIdx.x, t = threadIdx.x;
    gs[t] = g[(size_t)b * 512 + t];
    gs[t + 256] = g[(size_t)b * 512 + 256 + t];
    __syncthreads();
    float acc = b1[t];
#pragma unroll 8
    for (int k = 0; k < 512; k++)
        acc = fmaf(gs[k], w1[(size_t)k * 256 + t], acc);
    float hv = fmaxf(acc, 0.f);
    float p0 = hv * w2[t * 2 + 0];
    float p1 = hv * w2[t * 2 + 1];
#pragma unroll
    for (int off = 32; off; off >>= 1) {
        p0 += __shfl_down(p0, off);
        p1 += __shfl_down(p1, off);
    }
    int w = t >> 6;
    if ((t & 63) == 0) { parts[w][0] = p0; parts[w][1] = p1; }
    __syncthreads();
    if (t == 0) {
        out[b * 2 + 0] = parts[0][0] + parts[1][0] + parts[2][0] + parts[3][0] + b2[0];
        out[b * 2 + 1] = parts[0][1] + parts[1][1] + parts[2][1] + parts[3][1] + b2[1];
    }
}

// ---------------- launch ----------------
extern "C" void kernel_launch(void* const* d_in, const int* in_sizes, int n_in,
                              void* d_out, int out_size, void* d_ws, size_t ws_size,
                              hipStream_t stream) {
    const float* x     = (const float*)d_in[0];
    const float* xda   = (const float*)d_in[1];
    const int*   ei    = (const int*)d_in[2];
    const int*   root  = (const int*)d_in[4];
    const float* td_w1 = (const float*)d_in[5];
    const float* td_b1 = (const float*)d_in[6];
    const float* td_w2 = (const float*)d_in[7];
    const float* td_b2 = (const float*)d_in[8];
    const float* bu_w1 = (const float*)d_in[9];
    const float* bu_b1 = (const float*)d_in[10];
    const float* bu_w2 = (const float*)d_in[11];
    const float* bu_b2 = (const float*)d_in[12];
    const float* mw1   = (const float*)d_in[13];
    const float* mb1   = (const float*)d_in[14];
    const float* mw2   = (const float*)d_in[15];
    const float* mb2   = (const float*)d_in[16];
    float* out = (float*)d_out;

    // workspace layout
    ushortT* agg_bu  = (ushortT*)d_ws;                       // NN*128 bf16 (aliased by slabs in preproc)
    ushortT* agg_td  = agg_bu + (size_t)NN * 128;
    ushortT* hs_bu   = agg_td + (size_t)NN * 128;
    ushortT* hs_td   = hs_bu + (size_t)NN * 128;
    float*   dinv_td = (float*)(hs_td + (size_t)NN * 128);   // NN
    float*   dinv_bu = dinv_td + NN;                         // NN
    float*   x2_bu   = dinv_bu + NN;                         // NB*128
    float*   x2_td   = x2_bu + (size_t)NB * 128;
    float*   rm_bu   = x2_td + (size_t)NB * 128;             // NB*128
    float*   rm_td   = rm_bu + (size_t)NB * 128;
    float*   gbuf    = rm_td + (size_t)NB * 128;             // NB*512
    ushortT* wt1_bu  = (ushortT*)(gbuf + (size_t)NB * 512);  // 16384 each
    ushortT* wt1_td  = wt1_bu + 16384;
    ushortT* wt2_bu  = wt1_td + 16384;
    ushortT* wt2_td  = wt2_bu + 16384;
    int*     bcnt_td = (int*)(wt2_td + 16384);               // NBUK
    int*     bcnt_bu = bcnt_td + NBUK;                       // NBUK
    int*     bbase_td= bcnt_bu + NBUK;                       // NBUK+1
    int*     bbase_bu= bbase_td + NBUK + 1;                  // NBUK+1
    int*     rp_td   = bbase_bu + NBUK + 1;                  // NN+1
    int*     rp_bu   = rp_td + NN + 1;                       // NN+1
    int*     csr_td  = rp_bu + NN + 1;                       // NE
    int*     csr_bu  = csr_td + NE;                          // NE
    int*     st_td   = (int*)agg_bu;                         // NBUK*SLAB ints (slab staging)
    int*     st_bu   = st_td + NBUK * SLAB;                  // NBUK*SLAB ints

    hipMemsetAsync(bcnt_td, 0, (size_t)(2 * NBUK) * sizeof(int), stream);

    wprep_k<<<4 * 64, 256, 0, stream>>>(bu_w1, td_w1, bu_w2, td_w2, wt1_bu);
    stage_slab_k<<<NEB2, 512, 0, stream>>>(ei, bcnt_td, bcnt_bu, st_td, st_bu);
    bscan_k<<<2, 1024, 0, stream>>>(bcnt_td, bcnt_bu, bbase_td, bbase_bu);
    place2_k<<<2 * NBUK, 256, 0, stream>>>(st_td, st_bu, bcnt_td, bcnt_bu,
                                           bbase_td, bbase_bu,
                                           rp_td, rp_bu, csr_td, csr_bu, dinv_td, dinv_bu);

    // conv1 (both branches fused, MFMA)
    gemm1x_k<<<NBLK, 256, 0, stream>>>(x, xda, wt1_bu, wt1_td, dinv_bu, dinv_td, hs_bu, hs_td);
    gather16_k<0><<<(NN + 15) / 16, 256, 0, stream>>>(
        rp_bu, csr_bu, dinv_bu, hs_bu, bu_b1,
        rp_td, csr_td, dinv_td, hs_td, td_b1, agg_bu, agg_td);

    roots_k<<<NB, 256, 0, stream>>>(x, xda, root, agg_bu, agg_td, bu_w2, td_w2,
                                    x2_bu, x2_td, rm_bu, rm_td);

    // conv2 (both branches in one grid, MFMA)
    gemm2x_k<<<2 * NBLK, 256, 0, stream>>>(agg_bu, agg_td, wt2_bu, wt2_td,
                                           rm_bu, rm_td, dinv_bu, dinv_td, hs_bu, hs_td);
    gather16_k<1><<<(NN + 15) / 16, 256, 0, stream>>>(
        rp_bu, csr_bu, dinv_bu, hs_bu, bu_b2,
        rp_td, csr_td, dinv_td, hs_td, td_b2, agg_bu, agg_td);

    gmean_k<<<NB, 256, 0, stream>>>(agg_bu, agg_td, x2_bu, x2_td, gbuf);
    mlp_k<<<NB, 256, 0, stream>>>(gbuf, mw1, mb1, mw2, mb2, out);
}